// Round 1
// baseline (6953.104 us; speedup 1.0000x reference)
//
#include <hip/hip_runtime.h>
#include <math.h>

#define NN 100000
#define NE 1600000
#define KIN 128
#define HD 64
#define NC 10
#define NL 4
#define NG 200

using f4 = float4;

// ---------------- BN finalize: mean/rstd from sums, re-zero accumulators ----
__global__ __launch_bounds__(64) void bn_finalize(float* __restrict__ sum,
                                                  float* __restrict__ sumsq,
                                                  float* __restrict__ mean,
                                                  float* __restrict__ rstd) {
  int c = threadIdx.x;
  if (c < HD) {
    float s = sum[c], q = sumsq[c];
    float m = s * (1.0f / NN);
    float v = q * (1.0f / NN) - m * m;
    mean[c] = m;
    rstd[c] = rsqrtf(v + 1e-5f);
    sum[c] = 0.f;
    sumsq[c] = 0.f;
  }
}

// ---------------- edge scatter: neigh[dst] += h[src] ------------------------
__global__ __launch_bounds__(256) void scatter_kernel(const float* __restrict__ h,
                                                      const int* __restrict__ src,
                                                      const int* __restrict__ dst,
                                                      float* __restrict__ neigh) {
  int tid = threadIdx.x;
  int e = blockIdx.x * 16 + (tid >> 4);
  int q = tid & 15;
  int s = src[e];
  int d = dst[e];
  f4 v = *reinterpret_cast<const f4*>(&h[s * HD + q * 4]);
  float* np = &neigh[d * HD + q * 4];
  atomicAdd(np + 0, v.x);
  atomicAdd(np + 1, v.y);
  atomicAdd(np + 2, v.z);
  atomicAdd(np + 3, v.w);
}

// ---------------- fused GEMM -----------------------------------------------
// MODE 0: embed   out = X[N,128] @ W + b          ; pooled0 += out (per graph)
// MODE 1: gemm1   out = ((1+eps)*h + neigh) @ W + b ; accumulate BN stats
// MODE 2: gemm2   out = (relu(bn1(t1)) @ W + b) * snorm ; accumulate BN stats
// tile: 128 rows x 64 cols per block, 256 threads, thread tile 4r x 8c
template <int MODE>
__global__ __launch_bounds__(256) void gemm_kernel(
    const float* __restrict__ Xa, const float* __restrict__ Xb,
    const float* __restrict__ W, const float* __restrict__ bias,
    const float* __restrict__ eps_p, const float* __restrict__ bng,
    const float* __restrict__ bnb, const float* __restrict__ bnm,
    const float* __restrict__ bnr, const float* __restrict__ snorm,
    const int* __restrict__ gid, float* __restrict__ out,
    float* __restrict__ pooled0, float* __restrict__ bn_sum,
    float* __restrict__ bn_sumsq) {
  __shared__ float xsT[64 * 132];  // [k][r], stride 132 (16B aligned, bank-spread)
  __shared__ float ws[64 * 64];    // [k][c]
  const int tid = threadIdx.x;
  const int row0 = blockIdx.x * 128;
  const int cx = tid & 7;   // 8 col-groups of 8 cols
  const int ry = tid >> 3;  // 32 row-groups of 4 rows

  float acc[4][8];
#pragma unroll
  for (int r = 0; r < 4; ++r)
#pragma unroll
    for (int j = 0; j < 8; ++j) acc[r][j] = 0.f;

  const float epsv = (MODE == 1) ? (1.0f + eps_p[0]) : 0.0f;
  const int KT = (MODE == 0) ? 2 : 1;

  for (int kt = 0; kt < KT; ++kt) {
    if (kt > 0) __syncthreads();
    // stage W tile (64x64)
#pragma unroll
    for (int i = 0; i < 4; ++i) {
      int f4i = i * 256 + tid;
      *reinterpret_cast<f4*>(&ws[f4i * 4]) =
          *reinterpret_cast<const f4*>(&W[kt * 4096 + f4i * 4]);
    }
    // stage X tile (128 rows x 64 k), transposed into xsT[k][r]
#pragma unroll
    for (int i = 0; i < 8; ++i) {
      int f4i = i * 256 + tid;
      int r = f4i >> 4;
      int k4 = f4i & 15;
      int grow = row0 + r;
      f4 v = make_float4(0.f, 0.f, 0.f, 0.f);
      if (grow < NN) {
        if (MODE == 0) {
          v = *reinterpret_cast<const f4*>(&Xa[grow * KIN + kt * 64 + k4 * 4]);
        } else if (MODE == 1) {
          f4 va = *reinterpret_cast<const f4*>(&Xa[grow * HD + k4 * 4]);
          f4 vb = *reinterpret_cast<const f4*>(&Xb[grow * HD + k4 * 4]);
          v.x = epsv * va.x + vb.x;
          v.y = epsv * va.y + vb.y;
          v.z = epsv * va.z + vb.z;
          v.w = epsv * va.w + vb.w;
        } else {
          f4 va = *reinterpret_cast<const f4*>(&Xa[grow * HD + k4 * 4]);
          int k0 = k4 * 4;
          float t0 = bng[k0 + 0] * (va.x - bnm[k0 + 0]) * bnr[k0 + 0] + bnb[k0 + 0];
          float t1 = bng[k0 + 1] * (va.y - bnm[k0 + 1]) * bnr[k0 + 1] + bnb[k0 + 1];
          float t2 = bng[k0 + 2] * (va.z - bnm[k0 + 2]) * bnr[k0 + 2] + bnb[k0 + 2];
          float t3 = bng[k0 + 3] * (va.w - bnm[k0 + 3]) * bnr[k0 + 3] + bnb[k0 + 3];
          v.x = t0 > 0.f ? t0 : 0.f;
          v.y = t1 > 0.f ? t1 : 0.f;
          v.z = t2 > 0.f ? t2 : 0.f;
          v.w = t3 > 0.f ? t3 : 0.f;
        }
      }
      xsT[(k4 * 4 + 0) * 132 + r] = v.x;
      xsT[(k4 * 4 + 1) * 132 + r] = v.y;
      xsT[(k4 * 4 + 2) * 132 + r] = v.z;
      xsT[(k4 * 4 + 3) * 132 + r] = v.w;
    }
    __syncthreads();

#pragma unroll 8
    for (int k = 0; k < 64; ++k) {
      f4 xv = *reinterpret_cast<const f4*>(&xsT[k * 132 + ry * 4]);
      f4 wa = *reinterpret_cast<const f4*>(&ws[k * 64 + cx * 8]);
      f4 wb = *reinterpret_cast<const f4*>(&ws[k * 64 + cx * 8 + 4]);
      float xr[4] = {xv.x, xv.y, xv.z, xv.w};
      float wc[8] = {wa.x, wa.y, wa.z, wa.w, wb.x, wb.y, wb.z, wb.w};
#pragma unroll
      for (int r = 0; r < 4; ++r)
#pragma unroll
        for (int j = 0; j < 8; ++j) acc[r][j] += xr[r] * wc[j];
    }
  }

  // ---------------- epilogue ----------------
  float psum[8], psq[8];
#pragma unroll
  for (int j = 0; j < 8; ++j) {
    psum[j] = 0.f;
    psq[j] = 0.f;
  }
#pragma unroll
  for (int rr = 0; rr < 4; ++rr) {
    int grow = row0 + ry * 4 + rr;
    if (grow < NN) {
      float sn = (MODE == 2) ? snorm[grow] : 1.0f;
      float vals[8];
#pragma unroll
      for (int j = 0; j < 8; ++j) {
        float v = acc[rr][j] + bias[cx * 8 + j];
        if (MODE == 2) v *= sn;
        vals[j] = v;
      }
      *reinterpret_cast<f4*>(&out[grow * HD + cx * 8]) =
          make_float4(vals[0], vals[1], vals[2], vals[3]);
      *reinterpret_cast<f4*>(&out[grow * HD + cx * 8 + 4]) =
          make_float4(vals[4], vals[5], vals[6], vals[7]);
      if (MODE == 0) {
        int g = gid[grow];
#pragma unroll
        for (int j = 0; j < 8; ++j)
          atomicAdd(&pooled0[g * HD + cx * 8 + j], vals[j]);
      } else {
#pragma unroll
        for (int j = 0; j < 8; ++j) {
          psum[j] += vals[j];
          psq[j] += vals[j] * vals[j];
        }
      }
    }
  }
  if (MODE != 0) {
    __syncthreads();  // done reading xsT; reuse as reduction scratch
    float* red = xsT;  // [2][32][64]
#pragma unroll
    for (int j = 0; j < 8; ++j) {
      red[ry * 64 + cx * 8 + j] = psum[j];
      red[2048 + ry * 64 + cx * 8 + j] = psq[j];
    }
    __syncthreads();
    if (tid < 64) {
      float s = 0.f, q = 0.f;
      for (int r2 = 0; r2 < 32; ++r2) {
        s += red[r2 * 64 + tid];
        q += red[2048 + r2 * 64 + tid];
      }
      atomicAdd(&bn_sum[tid], s);
      atomicAdd(&bn_sumsq[tid], q);
    }
  }
}

// ---------------- layer tail: h = h_in + relu(bn2(t2)); pooled += h ---------
__global__ __launch_bounds__(256) void final_kernel(
    const float* __restrict__ t2, float* __restrict__ h,
    const float* __restrict__ g2p, const float* __restrict__ be2p,
    const float* __restrict__ mean2, const float* __restrict__ rstd2,
    const int* __restrict__ gid, float* __restrict__ pooledL) {
  int idx = blockIdx.x * 256 + threadIdx.x;  // float4 index
  int r = idx >> 4;
  int c0 = (idx & 15) * 4;
  f4 t = *reinterpret_cast<const f4*>(&t2[r * HD + c0]);
  f4 hv = *reinterpret_cast<const f4*>(&h[r * HD + c0]);
  float tt[4] = {t.x, t.y, t.z, t.w};
  float hh[4] = {hv.x, hv.y, hv.z, hv.w};
  float vals[4];
#pragma unroll
  for (int j = 0; j < 4; ++j) {
    int c = c0 + j;
    float v = g2p[c] * (tt[j] - mean2[c]) * rstd2[c] + be2p[c];
    v = v > 0.f ? v : 0.f;
    vals[j] = hh[j] + v;
  }
  *reinterpret_cast<f4*>(&h[r * HD + c0]) =
      make_float4(vals[0], vals[1], vals[2], vals[3]);
  int g = gid[r];
  float* pp = &pooledL[g * HD + c0];
#pragma unroll
  for (int j = 0; j < 4; ++j) atomicAdd(pp + j, vals[j]);
}

// ---------------- final readout: score = sum_i pooled_i @ Wlin_i + blin_i ---
__global__ __launch_bounds__(256) void score_kernel(
    const float* __restrict__ pooled, const float* __restrict__ Wlin,
    const float* __restrict__ blin, float* __restrict__ out) {
  int o = blockIdx.x * 256 + threadIdx.x;
  if (o >= NG * NC) return;
  int g = o / NC, c = o % NC;
  float s = 0.f;
  for (int i = 0; i <= NL; ++i) {
    s += blin[i * NC + c];
    const float* pg = &pooled[i * NG * HD + g * HD];
    const float* wl = &Wlin[i * HD * NC + c];
    float acc = 0.f;
#pragma unroll 8
    for (int k = 0; k < HD; ++k) acc += pg[k] * wl[k * NC];
    s += acc;
  }
  out[o] = s;
}

extern "C" void kernel_launch(void* const* d_in, const int* in_sizes, int n_in,
                              void* d_out, int out_size, void* d_ws,
                              size_t ws_size, hipStream_t stream) {
  const float* X = (const float*)d_in[0];
  const float* snorm = (const float*)d_in[1];
  const int* src = (const int*)d_in[2];
  const int* dst = (const int*)d_in[3];
  const int* gid = (const int*)d_in[4];
  const float* W_embed = (const float*)d_in[5];
  const float* b_embed = (const float*)d_in[6];
  const float* eps = (const float*)d_in[7];
  const float* W1 = (const float*)d_in[8];
  const float* b1 = (const float*)d_in[9];
  const float* g1 = (const float*)d_in[10];
  const float* be1 = (const float*)d_in[11];
  const float* W2 = (const float*)d_in[12];
  const float* b2 = (const float*)d_in[13];
  const float* g2 = (const float*)d_in[14];
  const float* be2 = (const float*)d_in[15];
  const float* Wlin = (const float*)d_in[16];
  const float* blin = (const float*)d_in[17];

  float* ws = (float*)d_ws;
  float* h_buf = ws;                          // N*64
  float* neigh = h_buf + (size_t)NN * HD;     // N*64 (also reused as t2)
  float* t1 = neigh + (size_t)NN * HD;        // N*64
  float* pooled = t1 + (size_t)NN * HD;       // 5*200*64
  float* stats = pooled + 5 * NG * HD;        // 384: sum,sumsq,mean1,rstd1,mean2,rstd2

  // zero pooled + stats (also clears 0xAA poison at timing start)
  hipMemsetAsync(pooled, 0, (5 * NG * HD + 384) * sizeof(float), stream);

  const int GEMM_GRID = (NN + 127) / 128;  // 782

  gemm_kernel<0><<<GEMM_GRID, 256, 0, stream>>>(
      X, nullptr, W_embed, b_embed, nullptr, nullptr, nullptr, nullptr, nullptr,
      nullptr, gid, h_buf, pooled, nullptr, nullptr);

  for (int l = 0; l < NL; ++l) {
    hipMemsetAsync(neigh, 0, (size_t)NN * HD * sizeof(float), stream);
    scatter_kernel<<<NE / 16, 256, 0, stream>>>(h_buf, src, dst, neigh);
    gemm_kernel<1><<<GEMM_GRID, 256, 0, stream>>>(
        h_buf, neigh, W1 + l * 4096, b1 + l * 64, eps + l, nullptr, nullptr,
        nullptr, nullptr, nullptr, nullptr, t1, nullptr, stats + 0, stats + 64);
    bn_finalize<<<1, 64, 0, stream>>>(stats + 0, stats + 64, stats + 128,
                                      stats + 192);
    gemm_kernel<2><<<GEMM_GRID, 256, 0, stream>>>(
        t1, nullptr, W2 + l * 4096, b2 + l * 64, nullptr, g1 + l * 64,
        be1 + l * 64, stats + 128, stats + 192, snorm, nullptr, neigh, nullptr,
        stats + 0, stats + 64);
    bn_finalize<<<1, 64, 0, stream>>>(stats + 0, stats + 64, stats + 256,
                                      stats + 320);
    final_kernel<<<(NN * 16) / 256, 256, 0, stream>>>(
        neigh, h_buf, g2 + l * 64, be2 + l * 64, stats + 256, stats + 320, gid,
        pooled + (l + 1) * NG * HD);
  }

  score_kernel<<<(NG * NC + 255) / 256, 256, 0, stream>>>(pooled, Wlin, blin,
                                                          (float*)d_out);
}

// Round 2
// 1974.484 us; speedup vs baseline: 3.5215x; 3.5215x over previous
//
#include <hip/hip_runtime.h>
#include <math.h>

#define NN 100000
#define NE 1600000
#define KIN 128
#define HD 64
#define NC 10
#define NL 4
#define NG 200

using f4 = float4;

// ---------------- CSR build ------------------------------------------------
__global__ __launch_bounds__(256) void hist_kernel(const int* __restrict__ dst,
                                                   int* __restrict__ deg) {
  int e = blockIdx.x * 256 + threadIdx.x;
  if (e < NE) atomicAdd(&deg[dst[e]], 1);
}

__global__ __launch_bounds__(256) void scan_partial(const int* __restrict__ deg,
                                                    int* __restrict__ partial) {
  __shared__ int s[256];
  int tid = threadIdx.x;
  int i = blockIdx.x * 256 + tid;
  s[tid] = (i < NN) ? deg[i] : 0;
  __syncthreads();
  for (int off = 128; off > 0; off >>= 1) {
    if (tid < off) s[tid] += s[tid + off];
    __syncthreads();
  }
  if (tid == 0) partial[blockIdx.x] = s[0];
}

__global__ __launch_bounds__(512) void scan_block(int* __restrict__ partial,
                                                  int nchunk) {
  __shared__ int s[512];
  int tid = threadIdx.x;
  int v = (tid < nchunk) ? partial[tid] : 0;
  s[tid] = v;
  __syncthreads();
  for (int off = 1; off < 512; off <<= 1) {
    int t = (tid >= off) ? s[tid - off] : 0;
    __syncthreads();
    s[tid] += t;
    __syncthreads();
  }
  if (tid < nchunk) partial[tid] = s[tid] - v;  // exclusive
}

__global__ __launch_bounds__(256) void scan_add(const int* __restrict__ deg,
                                                const int* __restrict__ partial,
                                                int* __restrict__ row_ptr,
                                                int* __restrict__ cursor) {
  __shared__ int s[256];
  int tid = threadIdx.x;
  int i = blockIdx.x * 256 + tid;
  int v = (i < NN) ? deg[i] : 0;
  s[tid] = v;
  __syncthreads();
  for (int off = 1; off < 256; off <<= 1) {
    int t = (tid >= off) ? s[tid - off] : 0;
    __syncthreads();
    s[tid] += t;
    __syncthreads();
  }
  int excl = s[tid] - v + partial[blockIdx.x];
  if (i < NN) {
    row_ptr[i] = excl;
    cursor[i] = excl;
  }
  if (i == 0) row_ptr[NN] = NE;
}

__global__ __launch_bounds__(256) void fill_kernel(const int* __restrict__ src,
                                                   const int* __restrict__ dst,
                                                   int* __restrict__ cursor,
                                                   int* __restrict__ csr_src) {
  int e = blockIdx.x * 256 + threadIdx.x;
  if (e < NE) {
    int p = atomicAdd(&cursor[dst[e]], 1);
    csr_src[p] = src[e];
  }
}

// ---------------- gather: agg[v] = (1+eps)*h[v] + sum_{u->v} h[u] -----------
__global__ __launch_bounds__(256) void gather_kernel(
    const float* __restrict__ h, const int* __restrict__ rp,
    const int* __restrict__ csrc, const float* __restrict__ eps_p,
    float* __restrict__ agg) {
  int node = blockIdx.x * 16 + (threadIdx.x >> 4);
  int lane = threadIdx.x & 15;
  if (node >= NN) return;
  int beg = rp[node], end = rp[node + 1];
  float epsv = 1.0f + eps_p[0];
  f4 self = *reinterpret_cast<const f4*>(&h[node * HD + lane * 4]);
  float ax = epsv * self.x, ay = epsv * self.y, az = epsv * self.z,
        aw = epsv * self.w;
  int e = beg;
  for (; e + 1 < end; e += 2) {
    int s0 = csrc[e], s1 = csrc[e + 1];
    f4 v0 = *reinterpret_cast<const f4*>(&h[s0 * HD + lane * 4]);
    f4 v1 = *reinterpret_cast<const f4*>(&h[s1 * HD + lane * 4]);
    ax += v0.x + v1.x;
    ay += v0.y + v1.y;
    az += v0.z + v1.z;
    aw += v0.w + v1.w;
  }
  if (e < end) {
    int s0 = csrc[e];
    f4 v0 = *reinterpret_cast<const f4*>(&h[s0 * HD + lane * 4]);
    ax += v0.x;
    ay += v0.y;
    az += v0.z;
    aw += v0.w;
  }
  *reinterpret_cast<f4*>(&agg[node * HD + lane * 4]) =
      make_float4(ax, ay, az, aw);
}

// ---------------- BN finalize ----------------------------------------------
__global__ __launch_bounds__(64) void bn_finalize(float* __restrict__ sum,
                                                  float* __restrict__ sumsq,
                                                  float* __restrict__ mean,
                                                  float* __restrict__ rstd) {
  int c = threadIdx.x;
  if (c < HD) {
    float s = sum[c], q = sumsq[c];
    float m = s * (1.0f / NN);
    float v = q * (1.0f / NN) - m * m;
    mean[c] = m;
    rstd[c] = rsqrtf(v + 1e-5f);
    sum[c] = 0.f;
    sumsq[c] = 0.f;
  }
}

// ---------------- fused GEMM -----------------------------------------------
// MODE 0: embed   out = X[N,128] @ W + b          ; pooled0 += out (per graph)
// MODE 1: gemm1   out = agg @ W + b               ; accumulate BN stats
// MODE 2: gemm2   out = (relu(bn1(t1)) @ W + b) * snorm ; accumulate BN stats
template <int MODE>
__global__ __launch_bounds__(256) void gemm_kernel(
    const float* __restrict__ Xa, const float* __restrict__ W,
    const float* __restrict__ bias, const float* __restrict__ bng,
    const float* __restrict__ bnb, const float* __restrict__ bnm,
    const float* __restrict__ bnr, const float* __restrict__ snorm,
    const int* __restrict__ gid, float* __restrict__ out,
    float* __restrict__ pooled0, float* __restrict__ bn_sum,
    float* __restrict__ bn_sumsq) {
  __shared__ float xsT[64 * 132];  // [k][r]
  __shared__ float ws[64 * 64];    // [k][c]
  const int tid = threadIdx.x;
  const int row0 = blockIdx.x * 128;
  const int cx = tid & 7;
  const int ry = tid >> 3;

  float acc[4][8];
#pragma unroll
  for (int r = 0; r < 4; ++r)
#pragma unroll
    for (int j = 0; j < 8; ++j) acc[r][j] = 0.f;

  const int KT = (MODE == 0) ? 2 : 1;

  for (int kt = 0; kt < KT; ++kt) {
    if (kt > 0) __syncthreads();
#pragma unroll
    for (int i = 0; i < 4; ++i) {
      int f4i = i * 256 + tid;
      *reinterpret_cast<f4*>(&ws[f4i * 4]) =
          *reinterpret_cast<const f4*>(&W[kt * 4096 + f4i * 4]);
    }
#pragma unroll
    for (int i = 0; i < 8; ++i) {
      int f4i = i * 256 + tid;
      int r = f4i >> 4;
      int k4 = f4i & 15;
      int grow = row0 + r;
      f4 v = make_float4(0.f, 0.f, 0.f, 0.f);
      if (grow < NN) {
        if (MODE == 0) {
          v = *reinterpret_cast<const f4*>(&Xa[grow * KIN + kt * 64 + k4 * 4]);
        } else if (MODE == 1) {
          v = *reinterpret_cast<const f4*>(&Xa[grow * HD + k4 * 4]);
        } else {
          f4 va = *reinterpret_cast<const f4*>(&Xa[grow * HD + k4 * 4]);
          int k0 = k4 * 4;
          float t0 = bng[k0 + 0] * (va.x - bnm[k0 + 0]) * bnr[k0 + 0] + bnb[k0 + 0];
          float t1 = bng[k0 + 1] * (va.y - bnm[k0 + 1]) * bnr[k0 + 1] + bnb[k0 + 1];
          float t2 = bng[k0 + 2] * (va.z - bnm[k0 + 2]) * bnr[k0 + 2] + bnb[k0 + 2];
          float t3 = bng[k0 + 3] * (va.w - bnm[k0 + 3]) * bnr[k0 + 3] + bnb[k0 + 3];
          v.x = t0 > 0.f ? t0 : 0.f;
          v.y = t1 > 0.f ? t1 : 0.f;
          v.z = t2 > 0.f ? t2 : 0.f;
          v.w = t3 > 0.f ? t3 : 0.f;
        }
      }
      xsT[(k4 * 4 + 0) * 132 + r] = v.x;
      xsT[(k4 * 4 + 1) * 132 + r] = v.y;
      xsT[(k4 * 4 + 2) * 132 + r] = v.z;
      xsT[(k4 * 4 + 3) * 132 + r] = v.w;
    }
    __syncthreads();

#pragma unroll 8
    for (int k = 0; k < 64; ++k) {
      f4 xv = *reinterpret_cast<const f4*>(&xsT[k * 132 + ry * 4]);
      f4 wa = *reinterpret_cast<const f4*>(&ws[k * 64 + cx * 8]);
      f4 wb = *reinterpret_cast<const f4*>(&ws[k * 64 + cx * 8 + 4]);
      float xr[4] = {xv.x, xv.y, xv.z, xv.w};
      float wc[8] = {wa.x, wa.y, wa.z, wa.w, wb.x, wb.y, wb.z, wb.w};
#pragma unroll
      for (int r = 0; r < 4; ++r)
#pragma unroll
        for (int j = 0; j < 8; ++j) acc[r][j] += xr[r] * wc[j];
    }
  }

  // epilogue
  float psum[8], psq[8];
#pragma unroll
  for (int j = 0; j < 8; ++j) {
    psum[j] = 0.f;
    psq[j] = 0.f;
  }
#pragma unroll
  for (int rr = 0; rr < 4; ++rr) {
    int grow = row0 + ry * 4 + rr;
    if (grow < NN) {
      float sn = (MODE == 2) ? snorm[grow] : 1.0f;
      float vals[8];
#pragma unroll
      for (int j = 0; j < 8; ++j) {
        float v = acc[rr][j] + bias[cx * 8 + j];
        if (MODE == 2) v *= sn;
        vals[j] = v;
      }
      *reinterpret_cast<f4*>(&out[grow * HD + cx * 8]) =
          make_float4(vals[0], vals[1], vals[2], vals[3]);
      *reinterpret_cast<f4*>(&out[grow * HD + cx * 8 + 4]) =
          make_float4(vals[4], vals[5], vals[6], vals[7]);
      if (MODE == 0) {
        int g = gid[grow];
#pragma unroll
        for (int j = 0; j < 8; ++j)
          atomicAdd(&pooled0[g * HD + cx * 8 + j], vals[j]);
      } else {
#pragma unroll
        for (int j = 0; j < 8; ++j) {
          psum[j] += vals[j];
          psq[j] += vals[j] * vals[j];
        }
      }
    }
  }
  if (MODE != 0) {
    __syncthreads();
    float* red = xsT;  // reuse as scratch [2][32][64]
#pragma unroll
    for (int j = 0; j < 8; ++j) {
      red[ry * 64 + cx * 8 + j] = psum[j];
      red[2048 + ry * 64 + cx * 8 + j] = psq[j];
    }
    __syncthreads();
    if (tid < 64) {
      float s = 0.f, q = 0.f;
      for (int r2 = 0; r2 < 32; ++r2) {
        s += red[r2 * 64 + tid];
        q += red[2048 + r2 * 64 + tid];
      }
      atomicAdd(&bn_sum[tid], s);
      atomicAdd(&bn_sumsq[tid], q);
    }
  }
}

// ---------------- layer tail ------------------------------------------------
__global__ __launch_bounds__(256) void final_kernel(
    const float* __restrict__ t2, float* __restrict__ h,
    const float* __restrict__ g2p, const float* __restrict__ be2p,
    const float* __restrict__ mean2, const float* __restrict__ rstd2,
    const int* __restrict__ gid, float* __restrict__ pooledL) {
  int idx = blockIdx.x * 256 + threadIdx.x;
  int r = idx >> 4;
  int c0 = (idx & 15) * 4;
  f4 t = *reinterpret_cast<const f4*>(&t2[r * HD + c0]);
  f4 hv = *reinterpret_cast<const f4*>(&h[r * HD + c0]);
  float tt[4] = {t.x, t.y, t.z, t.w};
  float hh[4] = {hv.x, hv.y, hv.z, hv.w};
  float vals[4];
#pragma unroll
  for (int j = 0; j < 4; ++j) {
    int c = c0 + j;
    float v = g2p[c] * (tt[j] - mean2[c]) * rstd2[c] + be2p[c];
    v = v > 0.f ? v : 0.f;
    vals[j] = hh[j] + v;
  }
  *reinterpret_cast<f4*>(&h[r * HD + c0]) =
      make_float4(vals[0], vals[1], vals[2], vals[3]);
  int g = gid[r];
  float* pp = &pooledL[g * HD + c0];
#pragma unroll
  for (int j = 0; j < 4; ++j) atomicAdd(pp + j, vals[j]);
}

// ---------------- final readout --------------------------------------------
__global__ __launch_bounds__(256) void score_kernel(
    const float* __restrict__ pooled, const float* __restrict__ Wlin,
    const float* __restrict__ blin, float* __restrict__ out) {
  int o = blockIdx.x * 256 + threadIdx.x;
  if (o >= NG * NC) return;
  int g = o / NC, c = o % NC;
  float s = 0.f;
  for (int i = 0; i <= NL; ++i) {
    s += blin[i * NC + c];
    const float* pg = &pooled[i * NG * HD + g * HD];
    const float* wl = &Wlin[i * HD * NC + c];
    float acc = 0.f;
#pragma unroll 8
    for (int k = 0; k < HD; ++k) acc += pg[k] * wl[k * NC];
    s += acc;
  }
  out[o] = s;
}

extern "C" void kernel_launch(void* const* d_in, const int* in_sizes, int n_in,
                              void* d_out, int out_size, void* d_ws,
                              size_t ws_size, hipStream_t stream) {
  const float* X = (const float*)d_in[0];
  const float* snorm = (const float*)d_in[1];
  const int* src = (const int*)d_in[2];
  const int* dst = (const int*)d_in[3];
  const int* gid = (const int*)d_in[4];
  const float* W_embed = (const float*)d_in[5];
  const float* b_embed = (const float*)d_in[6];
  const float* eps = (const float*)d_in[7];
  const float* W1 = (const float*)d_in[8];
  const float* b1 = (const float*)d_in[9];
  const float* g1 = (const float*)d_in[10];
  const float* be1 = (const float*)d_in[11];
  const float* W2 = (const float*)d_in[12];
  const float* b2 = (const float*)d_in[13];
  const float* g2 = (const float*)d_in[14];
  const float* be2 = (const float*)d_in[15];
  const float* Wlin = (const float*)d_in[16];
  const float* blin = (const float*)d_in[17];

  float* ws = (float*)d_ws;
  float* h_buf = ws;                       // N*64
  float* agg = h_buf + (size_t)NN * HD;    // N*64  (gather out; reused as t2)
  float* t1 = agg + (size_t)NN * HD;       // N*64
  float* pooled = t1 + (size_t)NN * HD;    // 5*200*64
  float* stats = pooled + 5 * NG * HD;     // 384
  int* row_ptr = (int*)(stats + 384);      // NN+1
  int* cursor = row_ptr + NN + 1;          // NN
  int* deg = cursor + NN;                  // NN
  int* partial = deg + NN;                 // 512
  int* csr_src = partial + 512;            // NE

  const int EB = (NE + 255) / 256;         // 6250
  const int NCHUNK = (NN + 255) / 256;     // 391
  const int GEMM_GRID = (NN + 127) / 128;  // 782

  hipMemsetAsync(pooled, 0, (5 * NG * HD + 384) * sizeof(float), stream);
  hipMemsetAsync(deg, 0, NN * sizeof(int), stream);

  // CSR build (once per call)
  hist_kernel<<<EB, 256, 0, stream>>>(dst, deg);
  scan_partial<<<NCHUNK, 256, 0, stream>>>(deg, partial);
  scan_block<<<1, 512, 0, stream>>>(partial, NCHUNK);
  scan_add<<<NCHUNK, 256, 0, stream>>>(deg, partial, row_ptr, cursor);
  fill_kernel<<<EB, 256, 0, stream>>>(src, dst, cursor, csr_src);

  gemm_kernel<0><<<GEMM_GRID, 256, 0, stream>>>(
      X, W_embed, b_embed, nullptr, nullptr, nullptr, nullptr, nullptr, gid,
      h_buf, pooled, nullptr, nullptr);

  for (int l = 0; l < NL; ++l) {
    gather_kernel<<<(NN + 15) / 16, 256, 0, stream>>>(h_buf, row_ptr, csr_src,
                                                      eps + l, agg);
    gemm_kernel<1><<<GEMM_GRID, 256, 0, stream>>>(
        agg, W1 + l * 4096, b1 + l * 64, nullptr, nullptr, nullptr, nullptr,
        nullptr, nullptr, t1, nullptr, stats + 0, stats + 64);
    bn_finalize<<<1, 64, 0, stream>>>(stats + 0, stats + 64, stats + 128,
                                      stats + 192);
    gemm_kernel<2><<<GEMM_GRID, 256, 0, stream>>>(
        t1, W2 + l * 4096, b2 + l * 64, g1 + l * 64, be1 + l * 64, stats + 128,
        stats + 192, snorm, nullptr, agg, nullptr, stats + 0, stats + 64);
    bn_finalize<<<1, 64, 0, stream>>>(stats + 0, stats + 64, stats + 256,
                                      stats + 320);
    final_kernel<<<(NN * 16) / 256, 256, 0, stream>>>(
        agg, h_buf, g2 + l * 64, be2 + l * 64, stats + 256, stats + 320, gid,
        pooled + (l + 1) * NG * HD);
  }

  score_kernel<<<(NG * NC + 255) / 256, 256, 0, stream>>>(pooled, Wlin, blin,
                                                          (float*)d_out);
}

// Round 3
// 1055.617 us; speedup vs baseline: 6.5868x; 1.8705x over previous
//
#include <hip/hip_runtime.h>
#include <math.h>

#define NN 100000
#define NE 1600000
#define KIN 128
#define HD 64
#define NC 10
#define NL 4
#define NG 200

using f4 = float4;

// ---------------- CSR build ------------------------------------------------
__global__ __launch_bounds__(256) void hist_kernel(const int* __restrict__ dst,
                                                   int* __restrict__ deg) {
  int e = blockIdx.x * 256 + threadIdx.x;
  if (e < NE) atomicAdd(&deg[dst[e]], 1);
}

__global__ __launch_bounds__(256) void scan_partial(const int* __restrict__ deg,
                                                    int* __restrict__ partial) {
  __shared__ int s[256];
  int tid = threadIdx.x;
  int i = blockIdx.x * 256 + tid;
  s[tid] = (i < NN) ? deg[i] : 0;
  __syncthreads();
  for (int off = 128; off > 0; off >>= 1) {
    if (tid < off) s[tid] += s[tid + off];
    __syncthreads();
  }
  if (tid == 0) partial[blockIdx.x] = s[0];
}

__global__ __launch_bounds__(512) void scan_block(int* __restrict__ partial,
                                                  int nchunk) {
  __shared__ int s[512];
  int tid = threadIdx.x;
  int v = (tid < nchunk) ? partial[tid] : 0;
  s[tid] = v;
  __syncthreads();
  for (int off = 1; off < 512; off <<= 1) {
    int t = (tid >= off) ? s[tid - off] : 0;
    __syncthreads();
    s[tid] += t;
    __syncthreads();
  }
  if (tid < nchunk) partial[tid] = s[tid] - v;  // exclusive
}

__global__ __launch_bounds__(256) void scan_add(const int* __restrict__ deg,
                                                const int* __restrict__ partial,
                                                int* __restrict__ row_ptr,
                                                int* __restrict__ cursor) {
  __shared__ int s[256];
  int tid = threadIdx.x;
  int i = blockIdx.x * 256 + tid;
  int v = (i < NN) ? deg[i] : 0;
  s[tid] = v;
  __syncthreads();
  for (int off = 1; off < 256; off <<= 1) {
    int t = (tid >= off) ? s[tid - off] : 0;
    __syncthreads();
    s[tid] += t;
    __syncthreads();
  }
  int excl = s[tid] - v + partial[blockIdx.x];
  if (i < NN) {
    row_ptr[i] = excl;
    cursor[i] = excl;
  }
  if (i == 0) row_ptr[NN] = NE;
}

__global__ __launch_bounds__(256) void fill_kernel(const int* __restrict__ src,
                                                   const int* __restrict__ dst,
                                                   int* __restrict__ cursor,
                                                   int* __restrict__ csr_src) {
  int e = blockIdx.x * 256 + threadIdx.x;
  if (e < NE) {
    int p = atomicAdd(&cursor[dst[e]], 1);
    csr_src[p] = src[e];
  }
}

// ---------------- graph segment starts (gid is sorted) ----------------------
__global__ __launch_bounds__(256) void gstart_kernel(const int* __restrict__ gid,
                                                     int* __restrict__ gstart) {
  int g = threadIdx.x + blockIdx.x * 256;
  if (g > NG) return;
  int lo = 0, hi = NN;
  while (lo < hi) {
    int mid = (lo + hi) >> 1;
    if (gid[mid] < g)
      lo = mid + 1;
    else
      hi = mid;
  }
  gstart[g] = lo;
}

// ---------------- pooling: pooled[g] = sum_{rows of g} h[r] -----------------
__global__ __launch_bounds__(256) void pool_kernel(const float* __restrict__ h,
                                                   const int* __restrict__ gstart,
                                                   float* __restrict__ pooledL) {
  __shared__ float red[4][64];
  int g = blockIdx.x;
  int c = threadIdx.x & 63;
  int rg = threadIdx.x >> 6;  // 4 row groups
  int beg = gstart[g], end = gstart[g + 1];
  float acc = 0.f;
  for (int r = beg + rg; r < end; r += 4) acc += h[r * HD + c];
  red[rg][c] = acc;
  __syncthreads();
  if (rg == 0)
    pooledL[g * HD + c] = red[0][c] + red[1][c] + red[2][c] + red[3][c];
}

// ---------------- gather: agg[v] = (1+eps)*h[v] + sum_{u->v} h[u] -----------
__global__ __launch_bounds__(256) void gather_kernel(
    const float* __restrict__ h, const int* __restrict__ rp,
    const int* __restrict__ csrc, const float* __restrict__ eps_p,
    float* __restrict__ agg) {
  int node = blockIdx.x * 16 + (threadIdx.x >> 4);
  int lane = threadIdx.x & 15;
  if (node >= NN) return;
  int beg = rp[node], end = rp[node + 1];
  float epsv = 1.0f + eps_p[0];
  f4 self = *reinterpret_cast<const f4*>(&h[node * HD + lane * 4]);
  float ax = epsv * self.x, ay = epsv * self.y, az = epsv * self.z,
        aw = epsv * self.w;
  int e = beg;
  for (; e + 1 < end; e += 2) {
    int s0 = csrc[e], s1 = csrc[e + 1];
    f4 v0 = *reinterpret_cast<const f4*>(&h[s0 * HD + lane * 4]);
    f4 v1 = *reinterpret_cast<const f4*>(&h[s1 * HD + lane * 4]);
    ax += v0.x + v1.x;
    ay += v0.y + v1.y;
    az += v0.z + v1.z;
    aw += v0.w + v1.w;
  }
  if (e < end) {
    int s0 = csrc[e];
    f4 v0 = *reinterpret_cast<const f4*>(&h[s0 * HD + lane * 4]);
    ax += v0.x;
    ay += v0.y;
    az += v0.z;
    aw += v0.w;
  }
  *reinterpret_cast<f4*>(&agg[node * HD + lane * 4]) =
      make_float4(ax, ay, az, aw);
}

// ---------------- BN finalize ----------------------------------------------
__global__ __launch_bounds__(64) void bn_finalize(float* __restrict__ sum,
                                                  float* __restrict__ sumsq,
                                                  float* __restrict__ mean,
                                                  float* __restrict__ rstd) {
  int c = threadIdx.x;
  if (c < HD) {
    float s = sum[c], q = sumsq[c];
    float m = s * (1.0f / NN);
    float v = q * (1.0f / NN) - m * m;
    mean[c] = m;
    rstd[c] = rsqrtf(v + 1e-5f);
    sum[c] = 0.f;
    sumsq[c] = 0.f;
  }
}

// ---------------- fused GEMM -----------------------------------------------
// MODE 0: embed   out = X[N,128] @ W + b
// MODE 1: gemm1   out = agg @ W + b               ; accumulate BN stats
// MODE 2: gemm2   out = (relu(bn1(t1)) @ W + b) * snorm ; accumulate BN stats
template <int MODE>
__global__ __launch_bounds__(256) void gemm_kernel(
    const float* __restrict__ Xa, const float* __restrict__ W,
    const float* __restrict__ bias, const float* __restrict__ bng,
    const float* __restrict__ bnb, const float* __restrict__ bnm,
    const float* __restrict__ bnr, const float* __restrict__ snorm,
    float* __restrict__ out, float* __restrict__ bn_sum,
    float* __restrict__ bn_sumsq) {
  __shared__ float xsT[64 * 132];  // [k][r]
  __shared__ float ws[64 * 64];    // [k][c]
  const int tid = threadIdx.x;
  const int row0 = blockIdx.x * 128;
  const int cx = tid & 7;
  const int ry = tid >> 3;

  float acc[4][8];
#pragma unroll
  for (int r = 0; r < 4; ++r)
#pragma unroll
    for (int j = 0; j < 8; ++j) acc[r][j] = 0.f;

  const int KT = (MODE == 0) ? 2 : 1;

  for (int kt = 0; kt < KT; ++kt) {
    if (kt > 0) __syncthreads();
#pragma unroll
    for (int i = 0; i < 4; ++i) {
      int f4i = i * 256 + tid;
      *reinterpret_cast<f4*>(&ws[f4i * 4]) =
          *reinterpret_cast<const f4*>(&W[kt * 4096 + f4i * 4]);
    }
#pragma unroll
    for (int i = 0; i < 8; ++i) {
      int f4i = i * 256 + tid;
      int r = f4i >> 4;
      int k4 = f4i & 15;
      int grow = row0 + r;
      f4 v = make_float4(0.f, 0.f, 0.f, 0.f);
      if (grow < NN) {
        if (MODE == 0) {
          v = *reinterpret_cast<const f4*>(&Xa[grow * KIN + kt * 64 + k4 * 4]);
        } else if (MODE == 1) {
          v = *reinterpret_cast<const f4*>(&Xa[grow * HD + k4 * 4]);
        } else {
          f4 va = *reinterpret_cast<const f4*>(&Xa[grow * HD + k4 * 4]);
          int k0 = k4 * 4;
          float t0 = bng[k0 + 0] * (va.x - bnm[k0 + 0]) * bnr[k0 + 0] + bnb[k0 + 0];
          float t1 = bng[k0 + 1] * (va.y - bnm[k0 + 1]) * bnr[k0 + 1] + bnb[k0 + 1];
          float t2 = bng[k0 + 2] * (va.z - bnm[k0 + 2]) * bnr[k0 + 2] + bnb[k0 + 2];
          float t3 = bng[k0 + 3] * (va.w - bnm[k0 + 3]) * bnr[k0 + 3] + bnb[k0 + 3];
          v.x = t0 > 0.f ? t0 : 0.f;
          v.y = t1 > 0.f ? t1 : 0.f;
          v.z = t2 > 0.f ? t2 : 0.f;
          v.w = t3 > 0.f ? t3 : 0.f;
        }
      }
      xsT[(k4 * 4 + 0) * 132 + r] = v.x;
      xsT[(k4 * 4 + 1) * 132 + r] = v.y;
      xsT[(k4 * 4 + 2) * 132 + r] = v.z;
      xsT[(k4 * 4 + 3) * 132 + r] = v.w;
    }
    __syncthreads();

#pragma unroll 8
    for (int k = 0; k < 64; ++k) {
      f4 xv = *reinterpret_cast<const f4*>(&xsT[k * 132 + ry * 4]);
      f4 wa = *reinterpret_cast<const f4*>(&ws[k * 64 + cx * 8]);
      f4 wb = *reinterpret_cast<const f4*>(&ws[k * 64 + cx * 8 + 4]);
      float xr[4] = {xv.x, xv.y, xv.z, xv.w};
      float wc[8] = {wa.x, wa.y, wa.z, wa.w, wb.x, wb.y, wb.z, wb.w};
#pragma unroll
      for (int r = 0; r < 4; ++r)
#pragma unroll
        for (int j = 0; j < 8; ++j) acc[r][j] += xr[r] * wc[j];
    }
  }

  // epilogue
  float psum[8], psq[8];
#pragma unroll
  for (int j = 0; j < 8; ++j) {
    psum[j] = 0.f;
    psq[j] = 0.f;
  }
#pragma unroll
  for (int rr = 0; rr < 4; ++rr) {
    int grow = row0 + ry * 4 + rr;
    if (grow < NN) {
      float sn = (MODE == 2) ? snorm[grow] : 1.0f;
      float vals[8];
#pragma unroll
      for (int j = 0; j < 8; ++j) {
        float v = acc[rr][j] + bias[cx * 8 + j];
        if (MODE == 2) v *= sn;
        vals[j] = v;
      }
      *reinterpret_cast<f4*>(&out[grow * HD + cx * 8]) =
          make_float4(vals[0], vals[1], vals[2], vals[3]);
      *reinterpret_cast<f4*>(&out[grow * HD + cx * 8 + 4]) =
          make_float4(vals[4], vals[5], vals[6], vals[7]);
      if (MODE != 0) {
#pragma unroll
        for (int j = 0; j < 8; ++j) {
          psum[j] += vals[j];
          psq[j] += vals[j] * vals[j];
        }
      }
    }
  }
  if (MODE != 0) {
    __syncthreads();
    float* red = xsT;  // reuse as scratch [2][32][64]
#pragma unroll
    for (int j = 0; j < 8; ++j) {
      red[ry * 64 + cx * 8 + j] = psum[j];
      red[2048 + ry * 64 + cx * 8 + j] = psq[j];
    }
    __syncthreads();
    if (tid < 64) {
      float s = 0.f, q = 0.f;
      for (int r2 = 0; r2 < 32; ++r2) {
        s += red[r2 * 64 + tid];
        q += red[2048 + r2 * 64 + tid];
      }
      atomicAdd(&bn_sum[tid], s);
      atomicAdd(&bn_sumsq[tid], q);
    }
  }
}

// ---------------- layer tail: h = h_in + relu(bn2(t2)) ----------------------
__global__ __launch_bounds__(256) void final_kernel(
    const float* __restrict__ t2, float* __restrict__ h,
    const float* __restrict__ g2p, const float* __restrict__ be2p,
    const float* __restrict__ mean2, const float* __restrict__ rstd2) {
  int idx = blockIdx.x * 256 + threadIdx.x;
  int r = idx >> 4;
  int c0 = (idx & 15) * 4;
  f4 t = *reinterpret_cast<const f4*>(&t2[r * HD + c0]);
  f4 hv = *reinterpret_cast<const f4*>(&h[r * HD + c0]);
  float tt[4] = {t.x, t.y, t.z, t.w};
  float hh[4] = {hv.x, hv.y, hv.z, hv.w};
  float vals[4];
#pragma unroll
  for (int j = 0; j < 4; ++j) {
    int c = c0 + j;
    float v = g2p[c] * (tt[j] - mean2[c]) * rstd2[c] + be2p[c];
    v = v > 0.f ? v : 0.f;
    vals[j] = hh[j] + v;
  }
  *reinterpret_cast<f4*>(&h[r * HD + c0]) =
      make_float4(vals[0], vals[1], vals[2], vals[3]);
}

// ---------------- final readout --------------------------------------------
__global__ __launch_bounds__(256) void score_kernel(
    const float* __restrict__ pooled, const float* __restrict__ Wlin,
    const float* __restrict__ blin, float* __restrict__ out) {
  int o = blockIdx.x * 256 + threadIdx.x;
  if (o >= NG * NC) return;
  int g = o / NC, c = o % NC;
  float s = 0.f;
  for (int i = 0; i <= NL; ++i) {
    s += blin[i * NC + c];
    const float* pg = &pooled[i * NG * HD + g * HD];
    const float* wl = &Wlin[i * HD * NC + c];
    float acc = 0.f;
#pragma unroll 8
    for (int k = 0; k < HD; ++k) acc += pg[k] * wl[k * NC];
    s += acc;
  }
  out[o] = s;
}

extern "C" void kernel_launch(void* const* d_in, const int* in_sizes, int n_in,
                              void* d_out, int out_size, void* d_ws,
                              size_t ws_size, hipStream_t stream) {
  const float* X = (const float*)d_in[0];
  const float* snorm = (const float*)d_in[1];
  const int* src = (const int*)d_in[2];
  const int* dst = (const int*)d_in[3];
  const int* gid = (const int*)d_in[4];
  const float* W_embed = (const float*)d_in[5];
  const float* b_embed = (const float*)d_in[6];
  const float* eps = (const float*)d_in[7];
  const float* W1 = (const float*)d_in[8];
  const float* b1 = (const float*)d_in[9];
  const float* g1 = (const float*)d_in[10];
  const float* be1 = (const float*)d_in[11];
  const float* W2 = (const float*)d_in[12];
  const float* b2 = (const float*)d_in[13];
  const float* g2 = (const float*)d_in[14];
  const float* be2 = (const float*)d_in[15];
  const float* Wlin = (const float*)d_in[16];
  const float* blin = (const float*)d_in[17];

  float* ws = (float*)d_ws;
  float* h_buf = ws;                       // N*64
  float* agg = h_buf + (size_t)NN * HD;    // N*64  (gather out; reused as t2)
  float* t1 = agg + (size_t)NN * HD;       // N*64
  float* pooled = t1 + (size_t)NN * HD;    // 5*200*64
  float* stats = pooled + 5 * NG * HD;     // 384
  int* row_ptr = (int*)(stats + 384);      // NN+1
  int* cursor = row_ptr + NN + 1;          // NN
  int* deg = cursor + NN;                  // NN
  int* partial = deg + NN;                 // 512
  int* gstart = partial + 512;             // NG+1
  int* csr_src = gstart + NG + 1;          // NE

  const int EB = (NE + 255) / 256;         // 6250
  const int NCHUNK = (NN + 255) / 256;     // 391
  const int GEMM_GRID = (NN + 127) / 128;  // 782

  hipMemsetAsync(stats, 0, 384 * sizeof(float), stream);
  hipMemsetAsync(deg, 0, NN * sizeof(int), stream);

  // CSR build + graph offsets (once per call)
  hist_kernel<<<EB, 256, 0, stream>>>(dst, deg);
  scan_partial<<<NCHUNK, 256, 0, stream>>>(deg, partial);
  scan_block<<<1, 512, 0, stream>>>(partial, NCHUNK);
  scan_add<<<NCHUNK, 256, 0, stream>>>(deg, partial, row_ptr, cursor);
  fill_kernel<<<EB, 256, 0, stream>>>(src, dst, cursor, csr_src);
  gstart_kernel<<<1, 256, 0, stream>>>(gid, gstart);

  gemm_kernel<0><<<GEMM_GRID, 256, 0, stream>>>(
      X, W_embed, b_embed, nullptr, nullptr, nullptr, nullptr, nullptr, h_buf,
      nullptr, nullptr);
  pool_kernel<<<NG, 256, 0, stream>>>(h_buf, gstart, pooled);

  for (int l = 0; l < NL; ++l) {
    gather_kernel<<<(NN + 15) / 16, 256, 0, stream>>>(h_buf, row_ptr, csr_src,
                                                      eps + l, agg);
    gemm_kernel<1><<<GEMM_GRID, 256, 0, stream>>>(
        agg, W1 + l * 4096, b1 + l * 64, nullptr, nullptr, nullptr, nullptr,
        nullptr, t1, stats + 0, stats + 64);
    bn_finalize<<<1, 64, 0, stream>>>(stats + 0, stats + 64, stats + 128,
                                      stats + 192);
    gemm_kernel<2><<<GEMM_GRID, 256, 0, stream>>>(
        t1, W2 + l * 4096, b2 + l * 64, g1 + l * 64, be1 + l * 64, stats + 128,
        stats + 192, snorm, agg, stats + 0, stats + 64);
    bn_finalize<<<1, 64, 0, stream>>>(stats + 0, stats + 64, stats + 256,
                                      stats + 320);
    final_kernel<<<(NN * 16) / 256, 256, 0, stream>>>(
        agg, h_buf, g2 + l * 64, be2 + l * 64, stats + 256, stats + 320);
    pool_kernel<<<NG, 256, 0, stream>>>(h_buf, gstart,
                                        pooled + (l + 1) * NG * HD);
  }

  score_kernel<<<(NG * NC + 255) / 256, 256, 0, stream>>>(pooled, Wlin, blin,
                                                          (float*)d_out);
}

// Round 4
// 822.851 us; speedup vs baseline: 8.4500x; 1.2829x over previous
//
#include <hip/hip_runtime.h>
#include <hip/hip_bf16.h>
#include <math.h>

#define NN 100000
#define NE 1600000
#define KIN 128
#define HD 64
#define NC 10
#define NL 4
#define NG 200
#define NBKT 196  // buckets of 512 nodes: bucket = dst >> 9

using f4 = float4;

// ======================= CSR build via 2-level counting sort ================
__global__ __launch_bounds__(256) void bucket_hist(const int* __restrict__ dst,
                                                   int* __restrict__ gbucket) {
  __shared__ int lh[NBKT];
  int tid = threadIdx.x;
  for (int i = tid; i < NBKT; i += 256) lh[i] = 0;
  __syncthreads();
  int base = blockIdx.x * 4096;
#pragma unroll 4
  for (int it = 0; it < 16; ++it) {
    int e = base + it * 256 + tid;
    if (e < NE) atomicAdd(&lh[dst[e] >> 9], 1);
  }
  __syncthreads();
  for (int i = tid; i < NBKT; i += 256)
    if (lh[i]) atomicAdd(&gbucket[i], lh[i]);
}

__global__ __launch_bounds__(256) void bucket_scan(const int* __restrict__ gbucket,
                                                   int* __restrict__ bbase,
                                                   int* __restrict__ bcur) {
  __shared__ int s[256];
  int tid = threadIdx.x;
  int v = (tid < NBKT) ? gbucket[tid] : 0;
  s[tid] = v;
  __syncthreads();
  for (int off = 1; off < 256; off <<= 1) {
    int t = (tid >= off) ? s[tid - off] : 0;
    __syncthreads();
    s[tid] += t;
    __syncthreads();
  }
  int excl = s[tid] - v;
  if (tid <= NBKT) bbase[tid] = excl;  // bbase[NBKT] = NE
  if (tid < NBKT) bcur[tid] = excl;
}

__global__ __launch_bounds__(256) void bucket_scatter(const int* __restrict__ src,
                                                      const int* __restrict__ dst,
                                                      int* __restrict__ bcur,
                                                      int2* __restrict__ pairs) {
  __shared__ int lh[NBKT];
  __shared__ int lbase[NBKT];
  int tid = threadIdx.x;
  for (int i = tid; i < NBKT; i += 256) lh[i] = 0;
  __syncthreads();
  int base = blockIdx.x * 4096;
  int dloc[16], sloc[16];
#pragma unroll
  for (int it = 0; it < 16; ++it) {
    int e = base + it * 256 + tid;
    bool ok = e < NE;
    dloc[it] = ok ? dst[e] : -1;
    sloc[it] = ok ? src[e] : 0;
    if (ok) atomicAdd(&lh[dloc[it] >> 9], 1);
  }
  __syncthreads();
  for (int i = tid; i < NBKT; i += 256) {
    int c = lh[i];
    lbase[i] = c ? atomicAdd(&bcur[i], c) : 0;
    lh[i] = 0;  // reuse as local cursor
  }
  __syncthreads();
#pragma unroll
  for (int it = 0; it < 16; ++it) {
    int d = dloc[it];
    if (d >= 0) {
      int b = d >> 9;
      int p = lbase[b] + atomicAdd(&lh[b], 1);
      pairs[p] = make_int2(d, sloc[it]);
    }
  }
}

__global__ __launch_bounds__(256) void csr_build(const int2* __restrict__ pairs,
                                                 const int* __restrict__ bbase,
                                                 int* __restrict__ row_ptr,
                                                 int* __restrict__ csr_src) {
  __shared__ int deg[512];
  __shared__ int psum[256];
  __shared__ int cur[512];
  int b = blockIdx.x;
  int tid = threadIdx.x;
  int beg = bbase[b], end = bbase[b + 1];
  int node0 = b << 9;
  deg[tid] = 0;
  deg[tid + 256] = 0;
  __syncthreads();
  for (int i = beg + tid; i < end; i += 256)
    atomicAdd(&deg[pairs[i].x - node0], 1);
  __syncthreads();
  int a0 = deg[2 * tid], a1 = deg[2 * tid + 1];
  psum[tid] = a0 + a1;
  __syncthreads();
  for (int off = 1; off < 256; off <<= 1) {
    int t = (tid >= off) ? psum[tid - off] : 0;
    __syncthreads();
    psum[tid] += t;
    __syncthreads();
  }
  int pe = psum[tid] - (a0 + a1);
  int e0 = pe, e1 = pe + a0;
  cur[2 * tid] = e0;
  cur[2 * tid + 1] = e1;
  int n0 = node0 + 2 * tid, n1 = node0 + 2 * tid + 1;
  if (n0 < NN) row_ptr[n0] = beg + e0;
  if (n1 < NN) row_ptr[n1] = beg + e1;
  __syncthreads();
  for (int i = beg + tid; i < end; i += 256) {
    int2 pr = pairs[i];
    int p = atomicAdd(&cur[pr.x - node0], 1);
    csr_src[beg + p] = pr.y;
  }
  if (b == 0 && tid == 0) row_ptr[NN] = NE;
}

// ---------------- graph segment starts (gid is sorted) ----------------------
__global__ __launch_bounds__(256) void gstart_kernel(const int* __restrict__ gid,
                                                     int* __restrict__ gstart) {
  int g = threadIdx.x + blockIdx.x * 256;
  if (g > NG) return;
  int lo = 0, hi = NN;
  while (lo < hi) {
    int mid = (lo + hi) >> 1;
    if (gid[mid] < g)
      lo = mid + 1;
    else
      hi = mid;
  }
  gstart[g] = lo;
}

// ---------------- pooling ---------------------------------------------------
__global__ __launch_bounds__(256) void pool_kernel(const float* __restrict__ h,
                                                   const int* __restrict__ gstart,
                                                   float* __restrict__ pooledL) {
  __shared__ float red[4][64];
  int g = blockIdx.x;
  int c = threadIdx.x & 63;
  int rg = threadIdx.x >> 6;
  int beg = gstart[g], end = gstart[g + 1];
  float acc = 0.f;
  for (int r = beg + rg; r < end; r += 4) acc += h[r * HD + c];
  red[rg][c] = acc;
  __syncthreads();
  if (rg == 0)
    pooledL[g * HD + c] = red[0][c] + red[1][c] + red[2][c] + red[3][c];
}

// ---------------- gather: agg[v] = (1+eps)*h[v] + sum_{u->v} hbf[u] ---------
__global__ __launch_bounds__(256) void gather_kernel(
    const float* __restrict__ h, const ushort* __restrict__ hbf,
    const int* __restrict__ rp, const int* __restrict__ csrc,
    const float* __restrict__ eps_p, float* __restrict__ agg) {
  int node = blockIdx.x * 32 + (threadIdx.x >> 3);
  int lane = threadIdx.x & 7;
  if (node >= NN) return;
  int beg = rp[node], end = rp[node + 1];
  float epsv = 1.0f + eps_p[0];
  f4 sa = *reinterpret_cast<const f4*>(&h[node * HD + lane * 8]);
  f4 sb = *reinterpret_cast<const f4*>(&h[node * HD + lane * 8 + 4]);
  float acc[8] = {epsv * sa.x, epsv * sa.y, epsv * sa.z, epsv * sa.w,
                  epsv * sb.x, epsv * sb.y, epsv * sb.z, epsv * sb.w};
  int e = beg;
  for (; e + 1 < end; e += 2) {
    int s0 = csrc[e], s1 = csrc[e + 1];
    f4 v0 = *reinterpret_cast<const f4*>(&hbf[s0 * HD + lane * 8]);
    f4 v1 = *reinterpret_cast<const f4*>(&hbf[s1 * HD + lane * 8]);
    const ushort* u0 = reinterpret_cast<const ushort*>(&v0);
    const ushort* u1 = reinterpret_cast<const ushort*>(&v1);
#pragma unroll
    for (int j = 0; j < 8; ++j)
      acc[j] += __uint_as_float(((unsigned)u0[j]) << 16) +
                __uint_as_float(((unsigned)u1[j]) << 16);
  }
  if (e < end) {
    int s0 = csrc[e];
    f4 v0 = *reinterpret_cast<const f4*>(&hbf[s0 * HD + lane * 8]);
    const ushort* u0 = reinterpret_cast<const ushort*>(&v0);
#pragma unroll
    for (int j = 0; j < 8; ++j)
      acc[j] += __uint_as_float(((unsigned)u0[j]) << 16);
  }
  *reinterpret_cast<f4*>(&agg[node * HD + lane * 8]) =
      make_float4(acc[0], acc[1], acc[2], acc[3]);
  *reinterpret_cast<f4*>(&agg[node * HD + lane * 8 + 4]) =
      make_float4(acc[4], acc[5], acc[6], acc[7]);
}

// ---------------- BN finalize ----------------------------------------------
__global__ __launch_bounds__(64) void bn_finalize(float* __restrict__ sum,
                                                  float* __restrict__ sumsq,
                                                  float* __restrict__ mean,
                                                  float* __restrict__ rstd) {
  int c = threadIdx.x;
  if (c < HD) {
    float s = sum[c], q = sumsq[c];
    float m = s * (1.0f / NN);
    float v = q * (1.0f / NN) - m * m;
    mean[c] = m;
    rstd[c] = rsqrtf(v + 1e-5f);
    sum[c] = 0.f;
    sumsq[c] = 0.f;
  }
}

// ---------------- fused GEMM -----------------------------------------------
// MODE 0: embed   out = X[N,128] @ W + b ; also writes bf16 mirror
// MODE 1: gemm1   out = agg @ W + b               ; accumulate BN stats
// MODE 2: gemm2   out = (relu(bn1(t1)) @ W + b) * snorm ; accumulate BN stats
template <int MODE>
__global__ __launch_bounds__(256) void gemm_kernel(
    const float* __restrict__ Xa, const float* __restrict__ W,
    const float* __restrict__ bias, const float* __restrict__ bng,
    const float* __restrict__ bnb, const float* __restrict__ bnm,
    const float* __restrict__ bnr, const float* __restrict__ snorm,
    float* __restrict__ out, float* __restrict__ bn_sum,
    float* __restrict__ bn_sumsq, ushort* __restrict__ hbf) {
  __shared__ float xsT[64 * 132];  // [k][r]
  __shared__ float ws[64 * 64];    // [k][c]
  const int tid = threadIdx.x;
  const int row0 = blockIdx.x * 128;
  const int cx = tid & 7;
  const int ry = tid >> 3;

  float acc[4][8];
#pragma unroll
  for (int r = 0; r < 4; ++r)
#pragma unroll
    for (int j = 0; j < 8; ++j) acc[r][j] = 0.f;

  const int KT = (MODE == 0) ? 2 : 1;

  for (int kt = 0; kt < KT; ++kt) {
    if (kt > 0) __syncthreads();
#pragma unroll
    for (int i = 0; i < 4; ++i) {
      int f4i = i * 256 + tid;
      *reinterpret_cast<f4*>(&ws[f4i * 4]) =
          *reinterpret_cast<const f4*>(&W[kt * 4096 + f4i * 4]);
    }
#pragma unroll
    for (int i = 0; i < 8; ++i) {
      int f4i = i * 256 + tid;
      int r = f4i >> 4;
      int k4 = f4i & 15;
      int grow = row0 + r;
      f4 v = make_float4(0.f, 0.f, 0.f, 0.f);
      if (grow < NN) {
        if (MODE == 0) {
          v = *reinterpret_cast<const f4*>(&Xa[grow * KIN + kt * 64 + k4 * 4]);
        } else if (MODE == 1) {
          v = *reinterpret_cast<const f4*>(&Xa[grow * HD + k4 * 4]);
        } else {
          f4 va = *reinterpret_cast<const f4*>(&Xa[grow * HD + k4 * 4]);
          int k0 = k4 * 4;
          float t0 = bng[k0 + 0] * (va.x - bnm[k0 + 0]) * bnr[k0 + 0] + bnb[k0 + 0];
          float t1 = bng[k0 + 1] * (va.y - bnm[k0 + 1]) * bnr[k0 + 1] + bnb[k0 + 1];
          float t2 = bng[k0 + 2] * (va.z - bnm[k0 + 2]) * bnr[k0 + 2] + bnb[k0 + 2];
          float t3 = bng[k0 + 3] * (va.w - bnm[k0 + 3]) * bnr[k0 + 3] + bnb[k0 + 3];
          v.x = t0 > 0.f ? t0 : 0.f;
          v.y = t1 > 0.f ? t1 : 0.f;
          v.z = t2 > 0.f ? t2 : 0.f;
          v.w = t3 > 0.f ? t3 : 0.f;
        }
      }
      xsT[(k4 * 4 + 0) * 132 + r] = v.x;
      xsT[(k4 * 4 + 1) * 132 + r] = v.y;
      xsT[(k4 * 4 + 2) * 132 + r] = v.z;
      xsT[(k4 * 4 + 3) * 132 + r] = v.w;
    }
    __syncthreads();

#pragma unroll 8
    for (int k = 0; k < 64; ++k) {
      f4 xv = *reinterpret_cast<const f4*>(&xsT[k * 132 + ry * 4]);
      f4 wa = *reinterpret_cast<const f4*>(&ws[k * 64 + cx * 8]);
      f4 wb = *reinterpret_cast<const f4*>(&ws[k * 64 + cx * 8 + 4]);
      float xr[4] = {xv.x, xv.y, xv.z, xv.w};
      float wc[8] = {wa.x, wa.y, wa.z, wa.w, wb.x, wb.y, wb.z, wb.w};
#pragma unroll
      for (int r = 0; r < 4; ++r)
#pragma unroll
        for (int j = 0; j < 8; ++j) acc[r][j] += xr[r] * wc[j];
    }
  }

  // epilogue
  float psum[8], psq[8];
#pragma unroll
  for (int j = 0; j < 8; ++j) {
    psum[j] = 0.f;
    psq[j] = 0.f;
  }
#pragma unroll
  for (int rr = 0; rr < 4; ++rr) {
    int grow = row0 + ry * 4 + rr;
    if (grow < NN) {
      float sn = (MODE == 2) ? snorm[grow] : 1.0f;
      float vals[8];
#pragma unroll
      for (int j = 0; j < 8; ++j) {
        float v = acc[rr][j] + bias[cx * 8 + j];
        if (MODE == 2) v *= sn;
        vals[j] = v;
      }
      *reinterpret_cast<f4*>(&out[grow * HD + cx * 8]) =
          make_float4(vals[0], vals[1], vals[2], vals[3]);
      *reinterpret_cast<f4*>(&out[grow * HD + cx * 8 + 4]) =
          make_float4(vals[4], vals[5], vals[6], vals[7]);
      if (MODE == 0) {
        union {
          f4 v;
          __hip_bfloat16 b[8];
        } pk;
#pragma unroll
        for (int j = 0; j < 8; ++j) pk.b[j] = __float2bfloat16(vals[j]);
        *reinterpret_cast<f4*>(&hbf[grow * HD + cx * 8]) = pk.v;
      } else {
#pragma unroll
        for (int j = 0; j < 8; ++j) {
          psum[j] += vals[j];
          psq[j] += vals[j] * vals[j];
        }
      }
    }
  }
  if (MODE != 0) {
    __syncthreads();
    float* red = xsT;
#pragma unroll
    for (int j = 0; j < 8; ++j) {
      red[ry * 64 + cx * 8 + j] = psum[j];
      red[2048 + ry * 64 + cx * 8 + j] = psq[j];
    }
    __syncthreads();
    if (tid < 64) {
      float s = 0.f, q = 0.f;
      for (int r2 = 0; r2 < 32; ++r2) {
        s += red[r2 * 64 + tid];
        q += red[2048 + r2 * 64 + tid];
      }
      atomicAdd(&bn_sum[tid], s);
      atomicAdd(&bn_sumsq[tid], q);
    }
  }
}

// ---------------- layer tail: h = h_in + relu(bn2(t2)); bf16 mirror ---------
__global__ __launch_bounds__(256) void final_kernel(
    const float* __restrict__ t2, float* __restrict__ h,
    ushort* __restrict__ hbf, const float* __restrict__ g2p,
    const float* __restrict__ be2p, const float* __restrict__ mean2,
    const float* __restrict__ rstd2) {
  int idx = blockIdx.x * 256 + threadIdx.x;  // 8-elem index
  int r = idx >> 3;
  int c0 = (idx & 7) * 8;
  f4 ta = *reinterpret_cast<const f4*>(&t2[r * HD + c0]);
  f4 tb = *reinterpret_cast<const f4*>(&t2[r * HD + c0 + 4]);
  f4 ha = *reinterpret_cast<const f4*>(&h[r * HD + c0]);
  f4 hb = *reinterpret_cast<const f4*>(&h[r * HD + c0 + 4]);
  float tt[8] = {ta.x, ta.y, ta.z, ta.w, tb.x, tb.y, tb.z, tb.w};
  float hh[8] = {ha.x, ha.y, ha.z, ha.w, hb.x, hb.y, hb.z, hb.w};
  float vals[8];
#pragma unroll
  for (int j = 0; j < 8; ++j) {
    int c = c0 + j;
    float v = g2p[c] * (tt[j] - mean2[c]) * rstd2[c] + be2p[c];
    v = v > 0.f ? v : 0.f;
    vals[j] = hh[j] + v;
  }
  *reinterpret_cast<f4*>(&h[r * HD + c0]) =
      make_float4(vals[0], vals[1], vals[2], vals[3]);
  *reinterpret_cast<f4*>(&h[r * HD + c0 + 4]) =
      make_float4(vals[4], vals[5], vals[6], vals[7]);
  union {
    f4 v;
    __hip_bfloat16 b[8];
  } pk;
#pragma unroll
  for (int j = 0; j < 8; ++j) pk.b[j] = __float2bfloat16(vals[j]);
  *reinterpret_cast<f4*>(&hbf[r * HD + c0]) = pk.v;
}

// ---------------- final readout --------------------------------------------
__global__ __launch_bounds__(256) void score_kernel(
    const float* __restrict__ pooled, const float* __restrict__ Wlin,
    const float* __restrict__ blin, float* __restrict__ out) {
  int o = blockIdx.x * 256 + threadIdx.x;
  if (o >= NG * NC) return;
  int g = o / NC, c = o % NC;
  float s = 0.f;
  for (int i = 0; i <= NL; ++i) {
    s += blin[i * NC + c];
    const float* pg = &pooled[i * NG * HD + g * HD];
    const float* wl = &Wlin[i * HD * NC + c];
    float acc = 0.f;
#pragma unroll 8
    for (int k = 0; k < HD; ++k) acc += pg[k] * wl[k * NC];
    s += acc;
  }
  out[o] = s;
}

extern "C" void kernel_launch(void* const* d_in, const int* in_sizes, int n_in,
                              void* d_out, int out_size, void* d_ws,
                              size_t ws_size, hipStream_t stream) {
  const float* X = (const float*)d_in[0];
  const float* snorm = (const float*)d_in[1];
  const int* src = (const int*)d_in[2];
  const int* dst = (const int*)d_in[3];
  const int* gid = (const int*)d_in[4];
  const float* W_embed = (const float*)d_in[5];
  const float* b_embed = (const float*)d_in[6];
  const float* eps = (const float*)d_in[7];
  const float* W1 = (const float*)d_in[8];
  const float* b1 = (const float*)d_in[9];
  const float* g1 = (const float*)d_in[10];
  const float* be1 = (const float*)d_in[11];
  const float* W2 = (const float*)d_in[12];
  const float* b2 = (const float*)d_in[13];
  const float* g2 = (const float*)d_in[14];
  const float* be2 = (const float*)d_in[15];
  const float* Wlin = (const float*)d_in[16];
  const float* blin = (const float*)d_in[17];

  float* ws = (float*)d_ws;
  float* h_buf = ws;                       // N*64 f32
  float* agg = h_buf + (size_t)NN * HD;    // N*64 (gather out / t2)
  float* t1 = agg + (size_t)NN * HD;       // N*64 (pairs overlaid during build)
  float* pooled = t1 + (size_t)NN * HD;    // 5*200*64
  float* stats = pooled + 5 * NG * HD;     // 384
  int* ib = (int*)(stats + 384);
  int* row_ptr = ib;                       // [0, 100004)
  int* gstart = ib + 100004;               // 204 (201 used)
  int* gbucket = ib + 100208;              // 196
  int* bbase = ib + 100404;                // 200 (197 used)
  int* bcur = ib + 100604;                 // 196
  int* csr_src = ib + 100800;              // NE
  ushort* h_bf = (ushort*)(ib + 100800 + NE);  // N*64 bf16
  int2* pairs = (int2*)t1;                 // NE int2, overlaid on t1

  const int GEMM_GRID = (NN + 127) / 128;  // 782
  const int EBLK = (NE + 4095) / 4096;     // 391

  hipMemsetAsync(stats, 0, 384 * sizeof(float), stream);
  hipMemsetAsync(gbucket, 0, NBKT * sizeof(int), stream);

  // CSR build (counting sort, once per call) + graph offsets
  bucket_hist<<<EBLK, 256, 0, stream>>>(dst, gbucket);
  bucket_scan<<<1, 256, 0, stream>>>(gbucket, bbase, bcur);
  bucket_scatter<<<EBLK, 256, 0, stream>>>(src, dst, bcur, pairs);
  csr_build<<<NBKT, 256, 0, stream>>>(pairs, bbase, row_ptr, csr_src);
  gstart_kernel<<<1, 256, 0, stream>>>(gid, gstart);

  gemm_kernel<0><<<GEMM_GRID, 256, 0, stream>>>(
      X, W_embed, b_embed, nullptr, nullptr, nullptr, nullptr, nullptr, h_buf,
      nullptr, nullptr, h_bf);
  pool_kernel<<<NG, 256, 0, stream>>>(h_buf, gstart, pooled);

  for (int l = 0; l < NL; ++l) {
    gather_kernel<<<(NN + 31) / 32, 256, 0, stream>>>(h_buf, h_bf, row_ptr,
                                                      csr_src, eps + l, agg);
    gemm_kernel<1><<<GEMM_GRID, 256, 0, stream>>>(
        agg, W1 + l * 4096, b1 + l * 64, nullptr, nullptr, nullptr, nullptr,
        nullptr, t1, stats + 0, stats + 64, nullptr);
    bn_finalize<<<1, 64, 0, stream>>>(stats + 0, stats + 64, stats + 128,
                                      stats + 192);
    gemm_kernel<2><<<GEMM_GRID, 256, 0, stream>>>(
        t1, W2 + l * 4096, b2 + l * 64, g1 + l * 64, be1 + l * 64, stats + 128,
        stats + 192, snorm, agg, stats + 0, stats + 64, nullptr);
    bn_finalize<<<1, 64, 0, stream>>>(stats + 0, stats + 64, stats + 256,
                                      stats + 320);
    final_kernel<<<(NN * 8) / 256, 256, 0, stream>>>(
        agg, h_buf, h_bf, g2 + l * 64, be2 + l * 64, stats + 256, stats + 320);
    pool_kernel<<<NG, 256, 0, stream>>>(h_buf, gstart,
                                        pooled + (l + 1) * NG * HD);
  }

  score_kernel<<<(NG * NC + 255) / 256, 256, 0, stream>>>(pooled, Wlin, blin,
                                                          (float*)d_out);
}

// Round 5
// 712.472 us; speedup vs baseline: 9.7591x; 1.1549x over previous
//
#include <hip/hip_runtime.h>
#include <hip/hip_bf16.h>
#include <math.h>

#define NN 100000
#define NE 1600000
#define KIN 128
#define HD 64
#define NC 10
#define NL 4
#define NG 200
#define NBKT 196  // buckets of 512 nodes: bucket = dst >> 9

typedef short s16x8 __attribute__((ext_vector_type(8)));
typedef float f32x4 __attribute__((ext_vector_type(4)));
using f4 = float4;

static __device__ __forceinline__ ushort f2bf(float x) {
  __hip_bfloat16 b = __float2bfloat16(x);
  return *reinterpret_cast<ushort*>(&b);
}
static __device__ __forceinline__ float bf2f(ushort u) {
  return __uint_as_float(((unsigned)u) << 16);
}
static __device__ __forceinline__ s16x8 zero8() {
  s16x8 v;
#pragma unroll
  for (int i = 0; i < 8; ++i) v[i] = 0;
  return v;
}

// ======================= CSR build via 2-level counting sort ================
__global__ __launch_bounds__(256) void bucket_hist(const int* __restrict__ dst,
                                                   int* __restrict__ gbucket) {
  __shared__ int lh[NBKT];
  int tid = threadIdx.x;
  for (int i = tid; i < NBKT; i += 256) lh[i] = 0;
  __syncthreads();
  int base = blockIdx.x * 4096;
#pragma unroll 4
  for (int it = 0; it < 16; ++it) {
    int e = base + it * 256 + tid;
    if (e < NE) atomicAdd(&lh[dst[e] >> 9], 1);
  }
  __syncthreads();
  for (int i = tid; i < NBKT; i += 256)
    if (lh[i]) atomicAdd(&gbucket[i], lh[i]);
}

__global__ __launch_bounds__(256) void bucket_scan(const int* __restrict__ gbucket,
                                                   int* __restrict__ bbase,
                                                   int* __restrict__ bcur) {
  __shared__ int s[256];
  int tid = threadIdx.x;
  int v = (tid < NBKT) ? gbucket[tid] : 0;
  s[tid] = v;
  __syncthreads();
  for (int off = 1; off < 256; off <<= 1) {
    int t = (tid >= off) ? s[tid - off] : 0;
    __syncthreads();
    s[tid] += t;
    __syncthreads();
  }
  int excl = s[tid] - v;
  if (tid <= NBKT) bbase[tid] = excl;
  if (tid < NBKT) bcur[tid] = excl;
}

__global__ __launch_bounds__(256) void bucket_scatter(const int* __restrict__ src,
                                                      const int* __restrict__ dst,
                                                      int* __restrict__ bcur,
                                                      int2* __restrict__ pairs) {
  __shared__ int lh[NBKT];
  __shared__ int lbase[NBKT];
  int tid = threadIdx.x;
  for (int i = tid; i < NBKT; i += 256) lh[i] = 0;
  __syncthreads();
  int base = blockIdx.x * 4096;
  int dloc[16], sloc[16];
#pragma unroll
  for (int it = 0; it < 16; ++it) {
    int e = base + it * 256 + tid;
    bool ok = e < NE;
    dloc[it] = ok ? dst[e] : -1;
    sloc[it] = ok ? src[e] : 0;
    if (ok) atomicAdd(&lh[dloc[it] >> 9], 1);
  }
  __syncthreads();
  for (int i = tid; i < NBKT; i += 256) {
    int c = lh[i];
    lbase[i] = c ? atomicAdd(&bcur[i], c) : 0;
    lh[i] = 0;
  }
  __syncthreads();
#pragma unroll
  for (int it = 0; it < 16; ++it) {
    int d = dloc[it];
    if (d >= 0) {
      int b = d >> 9;
      int p = lbase[b] + atomicAdd(&lh[b], 1);
      pairs[p] = make_int2(d, sloc[it]);
    }
  }
}

__global__ __launch_bounds__(256) void csr_build(const int2* __restrict__ pairs,
                                                 const int* __restrict__ bbase,
                                                 int* __restrict__ row_ptr,
                                                 int* __restrict__ csr_src) {
  __shared__ int deg[512];
  __shared__ int psum[256];
  __shared__ int cur[512];
  int b = blockIdx.x;
  int tid = threadIdx.x;
  int beg = bbase[b], end = bbase[b + 1];
  int node0 = b << 9;
  deg[tid] = 0;
  deg[tid + 256] = 0;
  __syncthreads();
  for (int i = beg + tid; i < end; i += 256)
    atomicAdd(&deg[pairs[i].x - node0], 1);
  __syncthreads();
  int a0 = deg[2 * tid], a1 = deg[2 * tid + 1];
  psum[tid] = a0 + a1;
  __syncthreads();
  for (int off = 1; off < 256; off <<= 1) {
    int t = (tid >= off) ? psum[tid - off] : 0;
    __syncthreads();
    psum[tid] += t;
    __syncthreads();
  }
  int pe = psum[tid] - (a0 + a1);
  int e0 = pe, e1 = pe + a0;
  cur[2 * tid] = e0;
  cur[2 * tid + 1] = e1;
  int n0 = node0 + 2 * tid, n1 = node0 + 2 * tid + 1;
  if (n0 < NN) row_ptr[n0] = beg + e0;
  if (n1 < NN) row_ptr[n1] = beg + e1;
  __syncthreads();
  for (int i = beg + tid; i < end; i += 256) {
    int2 pr = pairs[i];
    int p = atomicAdd(&cur[pr.x - node0], 1);
    csr_src[beg + p] = pr.y;
  }
  if (b == 0 && tid == 0) row_ptr[NN] = NE;
}

// ---------------- graph segment starts (gid is sorted) ----------------------
__global__ __launch_bounds__(256) void gstart_kernel(const int* __restrict__ gid,
                                                     int* __restrict__ gstart) {
  int g = threadIdx.x + blockIdx.x * 256;
  if (g > NG) return;
  int lo = 0, hi = NN;
  while (lo < hi) {
    int mid = (lo + hi) >> 1;
    if (gid[mid] < g)
      lo = mid + 1;
    else
      hi = mid;
  }
  gstart[g] = lo;
}

// ---------------- weight packing into MFMA B-fragment layout ----------------
// tile t: [2 kh][4 nf][64 lane=(kg*16+col)][8 k] bf16 ; k = kh*32+kg*8+j
__global__ __launch_bounds__(256) void pack_weights(
    const float* __restrict__ Wemb, const float* __restrict__ W1,
    const float* __restrict__ W2, ushort* __restrict__ Wpk) {
  int t = blockIdx.x;
  const float* src = (t < 2)   ? Wemb + t * 4096
                     : (t < 6) ? W1 + (t - 2) * 4096
                               : W2 + (t - 6) * 4096;
  for (int idx = threadIdx.x; idx < 4096; idx += 256) {
    int k = idx >> 6, n = idx & 63;
    int dsti = ((k >> 5) * 4 + (n >> 4)) * 512 +
               (((k >> 3) & 3) * 16 + (n & 15)) * 8 + (k & 7);
    Wpk[t * 4096 + dsti] = f2bf(src[idx]);
  }
}

// ---------------- pooling (+ optional bf16 mirror write) --------------------
__global__ __launch_bounds__(256) void pool_kernel(const float* __restrict__ h,
                                                   const int* __restrict__ gstart,
                                                   float* __restrict__ pooledL,
                                                   ushort* __restrict__ hbf) {
  __shared__ float red[4][64];
  int g = blockIdx.x;
  int c = threadIdx.x & 63;
  int rg = threadIdx.x >> 6;
  int beg = gstart[g], end = gstart[g + 1];
  float acc = 0.f;
  for (int r = beg + rg; r < end; r += 4) {
    float v = h[r * HD + c];
    acc += v;
    if (hbf) hbf[r * HD + c] = f2bf(v);
  }
  red[rg][c] = acc;
  __syncthreads();
  if (rg == 0)
    pooledL[g * HD + c] = red[0][c] + red[1][c] + red[2][c] + red[3][c];
}

// ---------------- gather: agg_bf[v] = bf16((1+eps)*h[v] + sum h_bf[u]) ------
__global__ __launch_bounds__(256) void gather_kernel(
    const float* __restrict__ h, const ushort* __restrict__ hbf,
    const int* __restrict__ rp, const int* __restrict__ csrc,
    const float* __restrict__ eps_p, ushort* __restrict__ aggbf) {
  int node = blockIdx.x * 32 + (threadIdx.x >> 3);
  int lane = threadIdx.x & 7;
  if (node >= NN) return;
  int beg = rp[node], end = rp[node + 1];
  float epsv = 1.0f + eps_p[0];
  f4 sa = *reinterpret_cast<const f4*>(&h[node * HD + lane * 8]);
  f4 sb = *reinterpret_cast<const f4*>(&h[node * HD + lane * 8 + 4]);
  float acc[8] = {epsv * sa.x, epsv * sa.y, epsv * sa.z, epsv * sa.w,
                  epsv * sb.x, epsv * sb.y, epsv * sb.z, epsv * sb.w};
  int e = beg;
  for (; e + 1 < end; e += 2) {
    int s0 = csrc[e], s1 = csrc[e + 1];
    f4 v0 = *reinterpret_cast<const f4*>(&hbf[s0 * HD + lane * 8]);
    f4 v1 = *reinterpret_cast<const f4*>(&hbf[s1 * HD + lane * 8]);
    const ushort* u0 = reinterpret_cast<const ushort*>(&v0);
    const ushort* u1 = reinterpret_cast<const ushort*>(&v1);
#pragma unroll
    for (int j = 0; j < 8; ++j) acc[j] += bf2f(u0[j]) + bf2f(u1[j]);
  }
  if (e < end) {
    int s0 = csrc[e];
    f4 v0 = *reinterpret_cast<const f4*>(&hbf[s0 * HD + lane * 8]);
    const ushort* u0 = reinterpret_cast<const ushort*>(&v0);
#pragma unroll
    for (int j = 0; j < 8; ++j) acc[j] += bf2f(u0[j]);
  }
  alignas(16) ushort us[8];
#pragma unroll
  for (int j = 0; j < 8; ++j) us[j] = f2bf(acc[j]);
  *reinterpret_cast<s16x8*>(&aggbf[(size_t)node * HD + lane * 8]) =
      *reinterpret_cast<const s16x8*>(us);
}

// ---------------- MFMA GEMM ------------------------------------------------
// MODE 0: out = X[N,128] @ Wemb + b                  (KT=2 k-tiles)
// MODE 1: out = agg_bf @ W1 + b    ; bn stats -> bn_out
// MODE 2: out = (relu(bn1(t1)) @ W2 + b) * snorm ; bn stats -> bn_out
// 128 rows x 64 cols per block, 4 waves, wave = 32 rows (2 m-frags x 4 n-frags)
template <int MODE>
__global__ __launch_bounds__(256, 4) void gemm_kernel(
    const void* Xin, const ushort* __restrict__ wt,
    const float* __restrict__ bias, const float* __restrict__ bn_in,
    const float* __restrict__ g1p, const float* __restrict__ be1p,
    const float* __restrict__ snorm, float* out, float* __restrict__ bn_out) {
  __shared__ ushort lds_a[128 * 64];   // row-major, 16B-chunk XOR swizzle
  __shared__ ushort lds_b[4096];       // fragment-packed
  __shared__ float lds_red[2][4][64];
  __shared__ float lds_bn[2][64];

  const int tid = threadIdx.x;
  const int row0 = blockIdx.x * 128;
  const int w = tid >> 6;
  const int l = tid & 63;
  const int lr = l >> 4, lc = l & 15;

  if (MODE == 2) {
    if (tid < 64) {
      float s = bn_in[tid], q = bn_in[64 + tid];
      float m = s * (1.0f / NN);
      float r = rsqrtf(q * (1.0f / NN) - m * m + 1e-5f);
      float scl = g1p[tid] * r;
      lds_bn[0][tid] = scl;
      lds_bn[1][tid] = be1p[tid] - m * scl;
    }
    __syncthreads();
  }

  f32x4 acc[2][4];
#pragma unroll
  for (int mi = 0; mi < 2; ++mi)
#pragma unroll
    for (int nf = 0; nf < 4; ++nf)
#pragma unroll
      for (int r = 0; r < 4; ++r) acc[mi][nf][r] = 0.f;

  const int KT = (MODE == 0) ? 2 : 1;
  for (int kt = 0; kt < KT; ++kt) {
    if (kt) __syncthreads();
    // stage B (linear copy of pre-packed weights)
#pragma unroll
    for (int i = 0; i < 2; ++i) {
      int ch = i * 256 + tid;
      *reinterpret_cast<s16x8*>(&lds_b[ch * 8]) =
          *reinterpret_cast<const s16x8*>(&wt[kt * 4096 + ch * 8]);
    }
    // stage A (swizzled)
#pragma unroll
    for (int i = 0; i < 4; ++i) {
      int f8i = i * 256 + tid;
      int row = f8i >> 3, c8 = f8i & 7;
      int grow = row0 + row;
      s16x8 val = zero8();
      if (grow < NN) {
        if (MODE == 1) {
          val = *reinterpret_cast<const s16x8*>(
              reinterpret_cast<const ushort*>(Xin) + (size_t)grow * HD + c8 * 8);
        } else {
          const float* p =
              (MODE == 0)
                  ? reinterpret_cast<const float*>(Xin) + (size_t)grow * KIN + kt * 64 + c8 * 8
                  : reinterpret_cast<const float*>(Xin) + (size_t)grow * HD + c8 * 8;
          f4 x0 = *reinterpret_cast<const f4*>(p);
          f4 x1 = *reinterpret_cast<const f4*>(p + 4);
          float xv[8] = {x0.x, x0.y, x0.z, x0.w, x1.x, x1.y, x1.z, x1.w};
          if (MODE == 2) {
#pragma unroll
            for (int j = 0; j < 8; ++j) {
              int c = c8 * 8 + j;
              float v = xv[j] * lds_bn[0][c] + lds_bn[1][c];
              xv[j] = v > 0.f ? v : 0.f;
            }
          }
          alignas(16) ushort us[8];
#pragma unroll
          for (int j = 0; j < 8; ++j) us[j] = f2bf(xv[j]);
          val = *reinterpret_cast<const s16x8*>(us);
        }
      }
      int slot = c8 ^ (row & 7);
      *reinterpret_cast<s16x8*>(&lds_a[row * 64 + slot * 8]) = val;
    }
    __syncthreads();

    // compute: A-frag lane l: row=l&15(+m-offset), k=(l>>4)*8..+8
    s16x8 af[2][2];
#pragma unroll
    for (int mi = 0; mi < 2; ++mi)
#pragma unroll
      for (int kh = 0; kh < 2; ++kh) {
        int row = w * 32 + mi * 16 + lc;
        int slot = (kh * 4 + lr) ^ (row & 7);
        af[mi][kh] = *reinterpret_cast<const s16x8*>(&lds_a[row * 64 + slot * 8]);
      }
#pragma unroll
    for (int kh = 0; kh < 2; ++kh)
#pragma unroll
      for (int nf = 0; nf < 4; ++nf) {
        s16x8 bf = *reinterpret_cast<const s16x8*>(&lds_b[(kh * 4 + nf) * 512 + l * 8]);
#pragma unroll
        for (int mi = 0; mi < 2; ++mi)
          acc[mi][nf] = __builtin_amdgcn_mfma_f32_16x16x32_bf16(
              af[mi][kh], bf, acc[mi][nf], 0, 0, 0);
      }
  }

  // epilogue: D lane l reg r -> row=(l>>4)*4+r, col=l&15
  float bias_l[4];
#pragma unroll
  for (int nf = 0; nf < 4; ++nf) bias_l[nf] = bias[nf * 16 + lc];

  float psum[4] = {0.f, 0.f, 0.f, 0.f}, psq[4] = {0.f, 0.f, 0.f, 0.f};
#pragma unroll
  for (int mi = 0; mi < 2; ++mi)
#pragma unroll
    for (int r = 0; r < 4; ++r) {
      int grow = row0 + w * 32 + mi * 16 + lr * 4 + r;
      if (grow < NN) {
        float sn = (MODE == 2) ? snorm[grow] : 1.0f;
#pragma unroll
        for (int nf = 0; nf < 4; ++nf) {
          float v = acc[mi][nf][r] + bias_l[nf];
          if (MODE == 2) v *= sn;
          out[(size_t)grow * HD + nf * 16 + lc] = v;
          if (MODE != 0) {
            psum[nf] += v;
            psq[nf] += v * v;
          }
        }
      }
    }
  if (MODE != 0) {
#pragma unroll
    for (int nf = 0; nf < 4; ++nf) {
      psum[nf] += __shfl_xor(psum[nf], 16);
      psq[nf] += __shfl_xor(psq[nf], 16);
      psum[nf] += __shfl_xor(psum[nf], 32);
      psq[nf] += __shfl_xor(psq[nf], 32);
    }
    if (l < 16) {
#pragma unroll
      for (int nf = 0; nf < 4; ++nf) {
        lds_red[0][w][nf * 16 + l] = psum[nf];
        lds_red[1][w][nf * 16 + l] = psq[nf];
      }
    }
    __syncthreads();
    if (tid < 64) {
      float s = 0.f, q = 0.f;
#pragma unroll
      for (int w2 = 0; w2 < 4; ++w2) {
        s += lds_red[0][w2][tid];
        q += lds_red[1][w2][tid];
      }
      atomicAdd(&bn_out[tid], s);
      atomicAdd(&bn_out[64 + tid], q);
    }
  }
}

// ---------------- layer tail: h = h_in + relu(bn2(t2)); bf16 mirror ---------
__global__ __launch_bounds__(256) void final_kernel(
    const float* __restrict__ t2, float* __restrict__ h,
    ushort* __restrict__ hbf, const float* __restrict__ g2p,
    const float* __restrict__ be2p, const float* __restrict__ stats2) {
  __shared__ float sc[64], sh[64];
  int tid = threadIdx.x;
  if (tid < 64) {
    float s = stats2[tid], q = stats2[64 + tid];
    float m = s * (1.0f / NN);
    float r = rsqrtf(q * (1.0f / NN) - m * m + 1e-5f);
    float scl = g2p[tid] * r;
    sc[tid] = scl;
    sh[tid] = be2p[tid] - m * scl;
  }
  __syncthreads();
  int idx = blockIdx.x * 256 + tid;
  int r = idx >> 3;
  int c0 = (idx & 7) * 8;
  f4 ta = *reinterpret_cast<const f4*>(&t2[r * HD + c0]);
  f4 tb = *reinterpret_cast<const f4*>(&t2[r * HD + c0 + 4]);
  f4 ha = *reinterpret_cast<const f4*>(&h[r * HD + c0]);
  f4 hb = *reinterpret_cast<const f4*>(&h[r * HD + c0 + 4]);
  float tt[8] = {ta.x, ta.y, ta.z, ta.w, tb.x, tb.y, tb.z, tb.w};
  float hh[8] = {ha.x, ha.y, ha.z, ha.w, hb.x, hb.y, hb.z, hb.w};
  float vals[8];
#pragma unroll
  for (int j = 0; j < 8; ++j) {
    int c = c0 + j;
    float v = tt[j] * sc[c] + sh[c];
    v = v > 0.f ? v : 0.f;
    vals[j] = hh[j] + v;
  }
  *reinterpret_cast<f4*>(&h[r * HD + c0]) =
      make_float4(vals[0], vals[1], vals[2], vals[3]);
  *reinterpret_cast<f4*>(&h[r * HD + c0 + 4]) =
      make_float4(vals[4], vals[5], vals[6], vals[7]);
  alignas(16) ushort us[8];
#pragma unroll
  for (int j = 0; j < 8; ++j) us[j] = f2bf(vals[j]);
  *reinterpret_cast<s16x8*>(&hbf[r * HD + c0]) =
      *reinterpret_cast<const s16x8*>(us);
}

// ---------------- final readout --------------------------------------------
__global__ __launch_bounds__(256) void score_kernel(
    const float* __restrict__ pooled, const float* __restrict__ Wlin,
    const float* __restrict__ blin, float* __restrict__ out) {
  int o = blockIdx.x * 256 + threadIdx.x;
  if (o >= NG * NC) return;
  int g = o / NC, c = o % NC;
  float s = 0.f;
  for (int i = 0; i <= NL; ++i) {
    s += blin[i * NC + c];
    const float* pg = &pooled[i * NG * HD + g * HD];
    const float* wl = &Wlin[i * HD * NC + c];
    float acc = 0.f;
#pragma unroll 8
    for (int k = 0; k < HD; ++k) acc += pg[k] * wl[k * NC];
    s += acc;
  }
  out[o] = s;
}

extern "C" void kernel_launch(void* const* d_in, const int* in_sizes, int n_in,
                              void* d_out, int out_size, void* d_ws,
                              size_t ws_size, hipStream_t stream) {
  const float* X = (const float*)d_in[0];
  const float* snorm = (const float*)d_in[1];
  const int* src = (const int*)d_in[2];
  const int* dst = (const int*)d_in[3];
  const int* gid = (const int*)d_in[4];
  const float* W_embed = (const float*)d_in[5];
  const float* b_embed = (const float*)d_in[6];
  const float* eps = (const float*)d_in[7];
  const float* W1 = (const float*)d_in[8];
  const float* b1 = (const float*)d_in[9];
  const float* g1 = (const float*)d_in[10];
  const float* be1 = (const float*)d_in[11];
  const float* W2 = (const float*)d_in[12];
  const float* b2 = (const float*)d_in[13];
  const float* g2 = (const float*)d_in[14];
  const float* be2 = (const float*)d_in[15];
  const float* Wlin = (const float*)d_in[16];
  const float* blin = (const float*)d_in[17];

  float* ws = (float*)d_ws;
  float* h_buf = ws;                        // N*64 f32
  float* t1 = h_buf + (size_t)NN * HD;      // N*64 f32 (pairs overlay in build)
  float* pooled = t1 + (size_t)NN * HD;     // 5*200*64
  float* stats = pooled + 5 * NG * HD;      // NL*256: per layer {bn1 s,q | bn2 s,q}
  int* ib = (int*)(stats + NL * 256);
  int* row_ptr = ib;                        // 100004
  int* gstart = ib + 100004;                // 204
  int* gbucket = ib + 100208;               // 196
  int* bbase = ib + 100404;                 // 200
  int* bcur = ib + 100604;                  // 196
  int* csr_src = ib + 100800;               // NE
  ushort* h_bf = (ushort*)(ib + 100800 + NE);  // N*64 bf16
  ushort* agg_bf = h_bf + (size_t)NN * HD;     // N*64 bf16
  ushort* Wpk = agg_bf + (size_t)NN * HD;      // 10*4096 bf16
  int2* pairs = (int2*)t1;

  const int GEMM_GRID = (NN + 127) / 128;  // 782
  const int EBLK = (NE + 4095) / 4096;     // 391

  hipMemsetAsync(stats, 0, NL * 256 * sizeof(float), stream);
  hipMemsetAsync(gbucket, 0, NBKT * sizeof(int), stream);

  pack_weights<<<10, 256, 0, stream>>>(W_embed, W1, W2, Wpk);

  bucket_hist<<<EBLK, 256, 0, stream>>>(dst, gbucket);
  bucket_scan<<<1, 256, 0, stream>>>(gbucket, bbase, bcur);
  bucket_scatter<<<EBLK, 256, 0, stream>>>(src, dst, bcur, pairs);
  csr_build<<<NBKT, 256, 0, stream>>>(pairs, bbase, row_ptr, csr_src);
  gstart_kernel<<<1, 256, 0, stream>>>(gid, gstart);

  gemm_kernel<0><<<GEMM_GRID, 256, 0, stream>>>(
      X, Wpk, b_embed, nullptr, nullptr, nullptr, nullptr, h_buf, nullptr);
  pool_kernel<<<NG, 256, 0, stream>>>(h_buf, gstart, pooled, h_bf);

  for (int l = 0; l < NL; ++l) {
    float* st1 = stats + l * 256;        // bn1 sum/sumsq
    float* st2 = stats + l * 256 + 128;  // bn2 sum/sumsq
    gather_kernel<<<(NN + 31) / 32, 256, 0, stream>>>(h_buf, h_bf, row_ptr,
                                                      csr_src, eps + l, agg_bf);
    gemm_kernel<1><<<GEMM_GRID, 256, 0, stream>>>(
        agg_bf, Wpk + (2 + l) * 4096, b1 + l * 64, nullptr, nullptr, nullptr,
        nullptr, t1, st1);
    gemm_kernel<2><<<GEMM_GRID, 256, 0, stream>>>(
        t1, Wpk + (6 + l) * 4096, b2 + l * 64, st1, g1 + l * 64, be1 + l * 64,
        snorm, t1, st2);
    final_kernel<<<(NN * 8) / 256, 256, 0, stream>>>(
        t1, h_buf, h_bf, g2 + l * 64, be2 + l * 64, st2);
    pool_kernel<<<NG, 256, 0, stream>>>(h_buf, gstart,
                                        pooled + (l + 1) * NG * HD, nullptr);
  }

  score_kernel<<<(NG * NC + 255) / 256, 256, 0, stream>>>(pooled, Wlin, blin,
                                                          (float*)d_out);
}

// Round 6
// 589.698 us; speedup vs baseline: 11.7910x; 1.2082x over previous
//
#include <hip/hip_runtime.h>
#include <hip/hip_bf16.h>
#include <math.h>

#define NN 100000
#define NE 1600000
#define KIN 128
#define HD 64
#define NC 10
#define NL 4
#define NG 200
#define NBKT 196  // buckets of 512 nodes: bucket = dst >> 9

typedef short s16x8 __attribute__((ext_vector_type(8)));
typedef float f32x4 __attribute__((ext_vector_type(4)));
using f4 = float4;

static __device__ __forceinline__ ushort f2bf(float x) {
  __hip_bfloat16 b = __float2bfloat16(x);
  return *reinterpret_cast<ushort*>(&b);
}
static __device__ __forceinline__ float bf2f(ushort u) {
  return __uint_as_float(((unsigned)u) << 16);
}
static __device__ __forceinline__ s16x8 zero8() {
  s16x8 v;
#pragma unroll
  for (int i = 0; i < 8; ++i) v[i] = 0;
  return v;
}

// ======================= CSR build via 2-level counting sort ================
__global__ __launch_bounds__(256) void bucket_hist(const int* __restrict__ dst,
                                                   int* __restrict__ gbucket) {
  __shared__ int lh[NBKT];
  int tid = threadIdx.x;
  for (int i = tid; i < NBKT; i += 256) lh[i] = 0;
  __syncthreads();
  int base = blockIdx.x * 4096;
#pragma unroll 4
  for (int it = 0; it < 16; ++it) {
    int e = base + it * 256 + tid;
    if (e < NE) atomicAdd(&lh[dst[e] >> 9], 1);
  }
  __syncthreads();
  for (int i = tid; i < NBKT; i += 256)
    if (lh[i]) atomicAdd(&gbucket[i], lh[i]);
}

__global__ __launch_bounds__(256) void bucket_scan(const int* __restrict__ gbucket,
                                                   int* __restrict__ bbase,
                                                   int* __restrict__ bcur) {
  __shared__ int s[256];
  int tid = threadIdx.x;
  int v = (tid < NBKT) ? gbucket[tid] : 0;
  s[tid] = v;
  __syncthreads();
  for (int off = 1; off < 256; off <<= 1) {
    int t = (tid >= off) ? s[tid - off] : 0;
    __syncthreads();
    s[tid] += t;
    __syncthreads();
  }
  int excl = s[tid] - v;
  if (tid <= NBKT) bbase[tid] = excl;
  if (tid < NBKT) bcur[tid] = excl;
}

__global__ __launch_bounds__(256) void bucket_scatter(const int* __restrict__ src,
                                                      const int* __restrict__ dst,
                                                      int* __restrict__ bcur,
                                                      int2* __restrict__ pairs) {
  __shared__ int lh[NBKT];
  __shared__ int lbase[NBKT];
  int tid = threadIdx.x;
  for (int i = tid; i < NBKT; i += 256) lh[i] = 0;
  __syncthreads();
  int base = blockIdx.x * 4096;
  int dloc[16], sloc[16];
#pragma unroll
  for (int it = 0; it < 16; ++it) {
    int e = base + it * 256 + tid;
    bool ok = e < NE;
    dloc[it] = ok ? dst[e] : -1;
    sloc[it] = ok ? src[e] : 0;
    if (ok) atomicAdd(&lh[dloc[it] >> 9], 1);
  }
  __syncthreads();
  for (int i = tid; i < NBKT; i += 256) {
    int c = lh[i];
    lbase[i] = c ? atomicAdd(&bcur[i], c) : 0;
    lh[i] = 0;
  }
  __syncthreads();
#pragma unroll
  for (int it = 0; it < 16; ++it) {
    int d = dloc[it];
    if (d >= 0) {
      int b = d >> 9;
      int p = lbase[b] + atomicAdd(&lh[b], 1);
      pairs[p] = make_int2(d, sloc[it]);
    }
  }
}

__global__ __launch_bounds__(256) void csr_build(const int2* __restrict__ pairs,
                                                 const int* __restrict__ bbase,
                                                 int* __restrict__ row_ptr,
                                                 int* __restrict__ csr_src) {
  __shared__ int deg[512];
  __shared__ int psum[256];
  __shared__ int cur[512];
  int b = blockIdx.x;
  int tid = threadIdx.x;
  int beg = bbase[b], end = bbase[b + 1];
  int node0 = b << 9;
  deg[tid] = 0;
  deg[tid + 256] = 0;
  __syncthreads();
  for (int i = beg + tid; i < end; i += 256)
    atomicAdd(&deg[pairs[i].x - node0], 1);
  __syncthreads();
  int a0 = deg[2 * tid], a1 = deg[2 * tid + 1];
  psum[tid] = a0 + a1;
  __syncthreads();
  for (int off = 1; off < 256; off <<= 1) {
    int t = (tid >= off) ? psum[tid - off] : 0;
    __syncthreads();
    psum[tid] += t;
    __syncthreads();
  }
  int pe = psum[tid] - (a0 + a1);
  int e0 = pe, e1 = pe + a0;
  cur[2 * tid] = e0;
  cur[2 * tid + 1] = e1;
  int n0 = node0 + 2 * tid, n1 = node0 + 2 * tid + 1;
  if (n0 < NN) row_ptr[n0] = beg + e0;
  if (n1 < NN) row_ptr[n1] = beg + e1;
  __syncthreads();
  for (int i = beg + tid; i < end; i += 256) {
    int2 pr = pairs[i];
    int p = atomicAdd(&cur[pr.x - node0], 1);
    csr_src[beg + p] = pr.y;
  }
  if (b == 0 && tid == 0) row_ptr[NN] = NE;
}

// ---------------- graph segment starts (gid is sorted) ----------------------
__global__ __launch_bounds__(256) void gstart_kernel(const int* __restrict__ gid,
                                                     int* __restrict__ gstart) {
  int g = threadIdx.x + blockIdx.x * 256;
  if (g > NG) return;
  int lo = 0, hi = NN;
  while (lo < hi) {
    int mid = (lo + hi) >> 1;
    if (gid[mid] < g)
      lo = mid + 1;
    else
      hi = mid;
  }
  gstart[g] = lo;
}

// ---------------- weight packing into MFMA B-fragment layout ----------------
__global__ __launch_bounds__(256) void pack_weights(
    const float* __restrict__ Wemb, const float* __restrict__ W1,
    const float* __restrict__ W2, ushort* __restrict__ Wpk) {
  int t = blockIdx.x;
  const float* src = (t < 2)   ? Wemb + t * 4096
                     : (t < 6) ? W1 + (t - 2) * 4096
                               : W2 + (t - 6) * 4096;
  for (int idx = threadIdx.x; idx < 4096; idx += 256) {
    int k = idx >> 6, n = idx & 63;
    int dsti = ((k >> 5) * 4 + (n >> 4)) * 512 +
               (((k >> 3) & 3) * 16 + (n & 15)) * 8 + (k & 7);
    Wpk[t * 4096 + dsti] = f2bf(src[idx]);
  }
}

// ---------------- pooling: chunked, graph-boundary flush + atomics ----------
__global__ __launch_bounds__(256) void pool_kernel(const float* __restrict__ h,
                                                   const int* __restrict__ gid,
                                                   float* __restrict__ pooledL) {
  int tid = threadIdx.x;
  int c = tid & 63;
  int rg = tid >> 6;
  int r0 = blockIdx.x * 128;
  int rend = r0 + 128 < NN ? r0 + 128 : NN;
  int rstart = r0 + rg;
  int cur = gid[rstart < NN ? rstart : NN - 1];
  float acc = 0.f;
  for (int r = rstart; r < rend; r += 4) {
    int g = gid[r];
    if (g != cur) {
      atomicAdd(&pooledL[cur * HD + c], acc);
      acc = 0.f;
      cur = g;
    }
    acc += h[r * HD + c];
  }
  atomicAdd(&pooledL[cur * HD + c], acc);
}

// ---------------- gather: agg_bf[v] = bf16((1+eps)*h[v] + sum h_bf[u]) ------
__global__ __launch_bounds__(256) void gather_kernel(
    const float* __restrict__ h, const ushort* __restrict__ hbf,
    const int* __restrict__ rp, const int* __restrict__ csrc,
    const float* __restrict__ eps_p, ushort* __restrict__ aggbf) {
  int node = blockIdx.x * 32 + (threadIdx.x >> 3);
  int lane = threadIdx.x & 7;
  if (node >= NN) return;
  int beg = rp[node], end = rp[node + 1];
  float epsv = 1.0f + eps_p[0];
  f4 sa = *reinterpret_cast<const f4*>(&h[node * HD + lane * 8]);
  f4 sb = *reinterpret_cast<const f4*>(&h[node * HD + lane * 8 + 4]);
  float acc[8] = {epsv * sa.x, epsv * sa.y, epsv * sa.z, epsv * sa.w,
                  epsv * sb.x, epsv * sb.y, epsv * sb.z, epsv * sb.w};
  int e = beg;
  for (; e + 1 < end; e += 2) {
    int s0 = csrc[e], s1 = csrc[e + 1];
    f4 v0 = *reinterpret_cast<const f4*>(&hbf[s0 * HD + lane * 8]);
    f4 v1 = *reinterpret_cast<const f4*>(&hbf[s1 * HD + lane * 8]);
    const ushort* u0 = reinterpret_cast<const ushort*>(&v0);
    const ushort* u1 = reinterpret_cast<const ushort*>(&v1);
#pragma unroll
    for (int j = 0; j < 8; ++j) acc[j] += bf2f(u0[j]) + bf2f(u1[j]);
  }
  if (e < end) {
    int s0 = csrc[e];
    f4 v0 = *reinterpret_cast<const f4*>(&hbf[s0 * HD + lane * 8]);
    const ushort* u0 = reinterpret_cast<const ushort*>(&v0);
#pragma unroll
    for (int j = 0; j < 8; ++j) acc[j] += bf2f(u0[j]);
  }
  alignas(16) ushort us[8];
#pragma unroll
  for (int j = 0; j < 8; ++j) us[j] = f2bf(acc[j]);
  *reinterpret_cast<s16x8*>(&aggbf[(size_t)node * HD + lane * 8]) =
      *reinterpret_cast<const s16x8*>(us);
}

// ---------------- MFMA GEMM ------------------------------------------------
// MODE 0: out = X[N,128] @ Wemb + b ; writes h_bf mirror       (KT=2 k-tiles)
// MODE 1: out = agg_bf @ W1 + b    ; bn stats -> bn_out
// MODE 2: out = (relu(bn1(t1)) @ W2 + b) * snorm ; bn stats -> bn_out
template <int MODE>
__global__ __launch_bounds__(256, 4) void gemm_kernel(
    const void* Xin, const ushort* __restrict__ wt,
    const float* __restrict__ bias, const float* __restrict__ bn_in,
    const float* __restrict__ g1p, const float* __restrict__ be1p,
    const float* __restrict__ snorm, float* out, float* __restrict__ bn_out,
    ushort* __restrict__ hbf) {
  __shared__ ushort lds_a[128 * 64];   // row-major, 16B-chunk XOR swizzle
  __shared__ ushort lds_b[4096];       // fragment-packed
  __shared__ float lds_red[2][4][64];
  __shared__ float lds_bn[2][64];

  const int tid = threadIdx.x;
  const int row0 = blockIdx.x * 128;
  const int w = tid >> 6;
  const int l = tid & 63;
  const int lr = l >> 4, lc = l & 15;

  if (MODE == 2) {
    if (tid < 64) {
      float s = bn_in[tid], q = bn_in[64 + tid];
      float m = s * (1.0f / NN);
      float r = rsqrtf(q * (1.0f / NN) - m * m + 1e-5f);
      float scl = g1p[tid] * r;
      lds_bn[0][tid] = scl;
      lds_bn[1][tid] = be1p[tid] - m * scl;
    }
    __syncthreads();
  }

  f32x4 acc[2][4];
#pragma unroll
  for (int mi = 0; mi < 2; ++mi)
#pragma unroll
    for (int nf = 0; nf < 4; ++nf)
#pragma unroll
      for (int r = 0; r < 4; ++r) acc[mi][nf][r] = 0.f;

  const int KT = (MODE == 0) ? 2 : 1;
  for (int kt = 0; kt < KT; ++kt) {
    if (kt) __syncthreads();
    // stage B (linear copy of pre-packed weights)
#pragma unroll
    for (int i = 0; i < 2; ++i) {
      int ch = i * 256 + tid;
      *reinterpret_cast<s16x8*>(&lds_b[ch * 8]) =
          *reinterpret_cast<const s16x8*>(&wt[kt * 4096 + ch * 8]);
    }
    // stage A (swizzled)
#pragma unroll
    for (int i = 0; i < 4; ++i) {
      int f8i = i * 256 + tid;
      int row = f8i >> 3, c8 = f8i & 7;
      int grow = row0 + row;
      s16x8 val = zero8();
      if (grow < NN) {
        if (MODE == 1) {
          val = *reinterpret_cast<const s16x8*>(
              reinterpret_cast<const ushort*>(Xin) + (size_t)grow * HD + c8 * 8);
        } else {
          const float* p =
              (MODE == 0)
                  ? reinterpret_cast<const float*>(Xin) + (size_t)grow * KIN + kt * 64 + c8 * 8
                  : reinterpret_cast<const float*>(Xin) + (size_t)grow * HD + c8 * 8;
          f4 x0 = *reinterpret_cast<const f4*>(p);
          f4 x1 = *reinterpret_cast<const f4*>(p + 4);
          float xv[8] = {x0.x, x0.y, x0.z, x0.w, x1.x, x1.y, x1.z, x1.w};
          if (MODE == 2) {
#pragma unroll
            for (int j = 0; j < 8; ++j) {
              int c = c8 * 8 + j;
              float v = xv[j] * lds_bn[0][c] + lds_bn[1][c];
              xv[j] = v > 0.f ? v : 0.f;
            }
          }
          alignas(16) ushort us[8];
#pragma unroll
          for (int j = 0; j < 8; ++j) us[j] = f2bf(xv[j]);
          val = *reinterpret_cast<const s16x8*>(us);
        }
      }
      int slot = c8 ^ (row & 7);
      *reinterpret_cast<s16x8*>(&lds_a[row * 64 + slot * 8]) = val;
    }
    __syncthreads();

    s16x8 af[2][2];
#pragma unroll
    for (int mi = 0; mi < 2; ++mi)
#pragma unroll
      for (int kh = 0; kh < 2; ++kh) {
        int row = w * 32 + mi * 16 + lc;
        int slot = (kh * 4 + lr) ^ (row & 7);
        af[mi][kh] = *reinterpret_cast<const s16x8*>(&lds_a[row * 64 + slot * 8]);
      }
#pragma unroll
    for (int kh = 0; kh < 2; ++kh)
#pragma unroll
      for (int nf = 0; nf < 4; ++nf) {
        s16x8 bf = *reinterpret_cast<const s16x8*>(&lds_b[(kh * 4 + nf) * 512 + l * 8]);
#pragma unroll
        for (int mi = 0; mi < 2; ++mi)
          acc[mi][nf] = __builtin_amdgcn_mfma_f32_16x16x32_bf16(
              af[mi][kh], bf, acc[mi][nf], 0, 0, 0);
      }
  }

  // epilogue: D lane l reg r -> row=(l>>4)*4+r, col=l&15
  float bias_l[4];
#pragma unroll
  for (int nf = 0; nf < 4; ++nf) bias_l[nf] = bias[nf * 16 + lc];

  float psum[4] = {0.f, 0.f, 0.f, 0.f}, psq[4] = {0.f, 0.f, 0.f, 0.f};
#pragma unroll
  for (int mi = 0; mi < 2; ++mi)
#pragma unroll
    for (int r = 0; r < 4; ++r) {
      int grow = row0 + w * 32 + mi * 16 + lr * 4 + r;
      if (grow < NN) {
        float sn = (MODE == 2) ? snorm[grow] : 1.0f;
#pragma unroll
        for (int nf = 0; nf < 4; ++nf) {
          float v = acc[mi][nf][r] + bias_l[nf];
          if (MODE == 2) v *= sn;
          out[(size_t)grow * HD + nf * 16 + lc] = v;
          if (MODE == 0) {
            hbf[(size_t)grow * HD + nf * 16 + lc] = f2bf(v);
          } else {
            psum[nf] += v;
            psq[nf] += v * v;
          }
        }
      }
    }
  if (MODE != 0) {
#pragma unroll
    for (int nf = 0; nf < 4; ++nf) {
      psum[nf] += __shfl_xor(psum[nf], 16);
      psq[nf] += __shfl_xor(psq[nf], 16);
      psum[nf] += __shfl_xor(psum[nf], 32);
      psq[nf] += __shfl_xor(psq[nf], 32);
    }
    if (l < 16) {
#pragma unroll
      for (int nf = 0; nf < 4; ++nf) {
        lds_red[0][w][nf * 16 + l] = psum[nf];
        lds_red[1][w][nf * 16 + l] = psq[nf];
      }
    }
    __syncthreads();
    if (tid < 64) {
      float s = 0.f, q = 0.f;
#pragma unroll
      for (int w2 = 0; w2 < 4; ++w2) {
        s += lds_red[0][w2][tid];
        q += lds_red[1][w2][tid];
      }
      atomicAdd(&bn_out[tid], s);
      atomicAdd(&bn_out[64 + tid], q);
    }
  }
}

// ---------------- layer tail: h = h_in + relu(bn2(t2)); bf16 mirror ---------
__global__ __launch_bounds__(256) void final_kernel(
    const float* __restrict__ t2, float* __restrict__ h,
    ushort* __restrict__ hbf, const float* __restrict__ g2p,
    const float* __restrict__ be2p, const float* __restrict__ stats2) {
  __shared__ float sc[64], sh[64];
  int tid = threadIdx.x;
  if (tid < 64) {
    float s = stats2[tid], q = stats2[64 + tid];
    float m = s * (1.0f / NN);
    float r = rsqrtf(q * (1.0f / NN) - m * m + 1e-5f);
    float scl = g2p[tid] * r;
    sc[tid] = scl;
    sh[tid] = be2p[tid] - m * scl;
  }
  __syncthreads();
  int idx = blockIdx.x * 256 + tid;
  int r = idx >> 3;
  int c0 = (idx & 7) * 8;
  f4 ta = *reinterpret_cast<const f4*>(&t2[r * HD + c0]);
  f4 tb = *reinterpret_cast<const f4*>(&t2[r * HD + c0 + 4]);
  f4 ha = *reinterpret_cast<const f4*>(&h[r * HD + c0]);
  f4 hb = *reinterpret_cast<const f4*>(&h[r * HD + c0 + 4]);
  float tt[8] = {ta.x, ta.y, ta.z, ta.w, tb.x, tb.y, tb.z, tb.w};
  float hh[8] = {ha.x, ha.y, ha.z, ha.w, hb.x, hb.y, hb.z, hb.w};
  float vals[8];
#pragma unroll
  for (int j = 0; j < 8; ++j) {
    int c = c0 + j;
    float v = tt[j] * sc[c] + sh[c];
    v = v > 0.f ? v : 0.f;
    vals[j] = hh[j] + v;
  }
  *reinterpret_cast<f4*>(&h[r * HD + c0]) =
      make_float4(vals[0], vals[1], vals[2], vals[3]);
  *reinterpret_cast<f4*>(&h[r * HD + c0 + 4]) =
      make_float4(vals[4], vals[5], vals[6], vals[7]);
  alignas(16) ushort us[8];
#pragma unroll
  for (int j = 0; j < 8; ++j) us[j] = f2bf(vals[j]);
  *reinterpret_cast<s16x8*>(&hbf[r * HD + c0]) =
      *reinterpret_cast<const s16x8*>(us);
}

// ---------------- final readout --------------------------------------------
__global__ __launch_bounds__(256) void score_kernel(
    const float* __restrict__ pooled, const float* __restrict__ Wlin,
    const float* __restrict__ blin, float* __restrict__ out) {
  int o = blockIdx.x * 256 + threadIdx.x;
  if (o >= NG * NC) return;
  int g = o / NC, c = o % NC;
  float s = 0.f;
  for (int i = 0; i <= NL; ++i) {
    s += blin[i * NC + c];
    const float* pg = &pooled[i * NG * HD + g * HD];
    const float* wl = &Wlin[i * HD * NC + c];
    float acc = 0.f;
#pragma unroll 8
    for (int k = 0; k < HD; ++k) acc += pg[k] * wl[k * NC];
    s += acc;
  }
  out[o] = s;
}

extern "C" void kernel_launch(void* const* d_in, const int* in_sizes, int n_in,
                              void* d_out, int out_size, void* d_ws,
                              size_t ws_size, hipStream_t stream) {
  const float* X = (const float*)d_in[0];
  const float* snorm = (const float*)d_in[1];
  const int* src = (const int*)d_in[2];
  const int* dst = (const int*)d_in[3];
  const int* gid = (const int*)d_in[4];
  const float* W_embed = (const float*)d_in[5];
  const float* b_embed = (const float*)d_in[6];
  const float* eps = (const float*)d_in[7];
  const float* W1 = (const float*)d_in[8];
  const float* b1 = (const float*)d_in[9];
  const float* g1 = (const float*)d_in[10];
  const float* be1 = (const float*)d_in[11];
  const float* W2 = (const float*)d_in[12];
  const float* b2 = (const float*)d_in[13];
  const float* g2 = (const float*)d_in[14];
  const float* be2 = (const float*)d_in[15];
  const float* Wlin = (const float*)d_in[16];
  const float* blin = (const float*)d_in[17];

  float* ws = (float*)d_ws;
  float* h_buf = ws;                        // N*64 f32
  float* t1 = h_buf + (size_t)NN * HD;      // N*64 f32 (pairs overlay in build)
  float* pooled = t1 + (size_t)NN * HD;     // 5*200*64
  float* stats = pooled + 5 * NG * HD;      // NL*256: per layer {bn1 s,q | bn2 s,q}
  int* ib = (int*)(stats + NL * 256);
  int* row_ptr = ib;                        // 100004
  int* gstart = ib + 100004;                // 204
  int* gbucket = ib + 100208;               // 196
  int* bbase = ib + 100404;                 // 200
  int* bcur = ib + 100604;                  // 196
  int* csr_src = ib + 100800;               // NE
  ushort* h_bf = (ushort*)(ib + 100800 + NE);  // N*64 bf16
  ushort* agg_bf = h_bf + (size_t)NN * HD;     // N*64 bf16
  ushort* Wpk = agg_bf + (size_t)NN * HD;      // 10*4096 bf16
  int2* pairs = (int2*)t1;

  const int GEMM_GRID = (NN + 127) / 128;  // 782
  const int EBLK = (NE + 4095) / 4096;     // 391
  const int POOL_GRID = (NN + 127) / 128;  // 782

  // zero pooled (atomically accumulated) + stats
  hipMemsetAsync(pooled, 0, (5 * NG * HD + NL * 256) * sizeof(float), stream);
  hipMemsetAsync(gbucket, 0, NBKT * sizeof(int), stream);

  pack_weights<<<10, 256, 0, stream>>>(W_embed, W1, W2, Wpk);

  bucket_hist<<<EBLK, 256, 0, stream>>>(dst, gbucket);
  bucket_scan<<<1, 256, 0, stream>>>(gbucket, bbase, bcur);
  bucket_scatter<<<EBLK, 256, 0, stream>>>(src, dst, bcur, pairs);
  csr_build<<<NBKT, 256, 0, stream>>>(pairs, bbase, row_ptr, csr_src);
  gstart_kernel<<<1, 256, 0, stream>>>(gid, gstart);

  gemm_kernel<0><<<GEMM_GRID, 256, 0, stream>>>(
      X, Wpk, b_embed, nullptr, nullptr, nullptr, nullptr, h_buf, nullptr,
      h_bf);
  pool_kernel<<<POOL_GRID, 256, 0, stream>>>(h_buf, gid, pooled);

  for (int l = 0; l < NL; ++l) {
    float* st1 = stats + l * 256;        // bn1 sum/sumsq
    float* st2 = stats + l * 256 + 128;  // bn2 sum/sumsq
    gather_kernel<<<(NN + 31) / 32, 256, 0, stream>>>(h_buf, h_bf, row_ptr,
                                                      csr_src, eps + l, agg_bf);
    gemm_kernel<1><<<GEMM_GRID, 256, 0, stream>>>(
        agg_bf, Wpk + (2 + l) * 4096, b1 + l * 64, nullptr, nullptr, nullptr,
        nullptr, t1, st1, nullptr);
    gemm_kernel<2><<<GEMM_GRID, 256, 0, stream>>>(
        t1, Wpk + (6 + l) * 4096, b2 + l * 64, st1, g1 + l * 64, be1 + l * 64,
        snorm, t1, st2, nullptr);
    final_kernel<<<(NN * 8) / 256, 256, 0, stream>>>(
        t1, h_buf, h_bf, g2 + l * 64, be2 + l * 64, st2);
    pool_kernel<<<POOL_GRID, 256, 0, stream>>>(h_buf, gid,
                                               pooled + (l + 1) * NG * HD);
  }

  score_kernel<<<(NG * NC + 255) / 256, 256, 0, stream>>>(pooled, Wlin, blin,
                                                          (float*)d_out);
}